// Round 2
// baseline (14585.255 us; speedup 1.0000x reference)
//
#include <hip/hip_runtime.h>
#include <math.h>

#define NB 64
#define NT 512
#define ND 512
#define NH 256
#define NG 1024   // 4*H
#define NK 32
#define NBT (NB*NT)

__device__ __forceinline__ float sigf(float x) { return 1.f / (1.f + expf(-x)); }

// ---------------------------------------------------------------------------
// Weight prep: ww[(((dir*2+s)*4+vq)*128+u)*64 + k*16 + j4][e] =
//              Whh_dir[(k*256 + s*128 + u)*256 + (vq*64 + j4*4 + e)]
// ---------------------------------------------------------------------------
__global__ void k_wprep2(const float* __restrict__ Wf, const float* __restrict__ Wb,
                         float* __restrict__ ww) {
    int f = blockIdx.x * 256 + threadIdx.x;      // 0 .. 524287
    int e   = f & 3;
    int j4  = (f >> 2) & 15;
    int k   = (f >> 6) & 3;
    int u   = (f >> 8) & 127;
    int vq  = (f >> 15) & 3;
    int s   = (f >> 17) & 1;
    int dir = f >> 18;
    const float* W = dir ? Wb : Wf;
    ww[f] = W[(size_t)(k * 256 + s * 128 + u) * 256 + (vq * 64 + j4 * 4 + e)];
}

// ---------------------------------------------------------------------------
// Fused input projection GEMM (both dirs): xp_dir = x @ Wih_dir^T + b_dir
// 128x128 tile, 8x8 per thread, K-chunks of 16.
// ---------------------------------------------------------------------------
__global__ __launch_bounds__(256, 4)
void k_gemm_f(const float* __restrict__ x, const float* __restrict__ Wf,
              const float* __restrict__ Wb, const float* __restrict__ bf,
              const float* __restrict__ bb, float* __restrict__ xpF,
              float* __restrict__ xpB, int bxBase) {
    __shared__ float As[16][132];
    __shared__ float Bs[16][132];
    int tid = threadIdx.x;
    int bx = blockIdx.x + bxBase;
    int dir = bx >> 3;
    const float* W    = dir ? Wb : Wf;
    const float* bias = dir ? bb : bf;
    float* xp         = dir ? xpB : xpF;
    int r0 = blockIdx.y << 7;
    int g0 = (bx & 7) << 7;
    int rl = tid >> 1, k8 = (tid & 1) << 3;
    const float* xa = x + (size_t)(r0 + rl) * ND + k8;
    const float* wa = W + (size_t)(g0 + rl) * ND + k8;
    int tx = tid & 15, ty = tid >> 4;
    float acc[8][8] = {};
    for (int kt = 0; kt < ND; kt += 16) {
        float4 a0 = *(const float4*)(xa + kt);
        float4 a1 = *(const float4*)(xa + kt + 4);
        float4 w0 = *(const float4*)(wa + kt);
        float4 w1 = *(const float4*)(wa + kt + 4);
        As[k8+0][rl]=a0.x; As[k8+1][rl]=a0.y; As[k8+2][rl]=a0.z; As[k8+3][rl]=a0.w;
        As[k8+4][rl]=a1.x; As[k8+5][rl]=a1.y; As[k8+6][rl]=a1.z; As[k8+7][rl]=a1.w;
        Bs[k8+0][rl]=w0.x; Bs[k8+1][rl]=w0.y; Bs[k8+2][rl]=w0.z; Bs[k8+3][rl]=w0.w;
        Bs[k8+4][rl]=w1.x; Bs[k8+5][rl]=w1.y; Bs[k8+6][rl]=w1.z; Bs[k8+7][rl]=w1.w;
        __syncthreads();
        #pragma unroll
        for (int kk = 0; kk < 16; ++kk) {
            float4 av0 = *(const float4*)(&As[kk][ty << 3]);
            float4 av1 = *(const float4*)(&As[kk][(ty << 3) + 4]);
            float4 bv0 = *(const float4*)(&Bs[kk][tx << 3]);
            float4 bv1 = *(const float4*)(&Bs[kk][(tx << 3) + 4]);
            float aa[8] = {av0.x, av0.y, av0.z, av0.w, av1.x, av1.y, av1.z, av1.w};
            float bbv[8] = {bv0.x, bv0.y, bv0.z, bv0.w, bv1.x, bv1.y, bv1.z, bv1.w};
            #pragma unroll
            for (int i = 0; i < 8; ++i)
                #pragma unroll
                for (int j = 0; j < 8; ++j)
                    acc[i][j] += aa[i] * bbv[j];
        }
        __syncthreads();
    }
    float bv[8];
    #pragma unroll
    for (int j = 0; j < 8; ++j) bv[j] = bias[g0 + (tx << 3) + j];
    #pragma unroll
    for (int i = 0; i < 8; ++i) {
        float* orow = xp + (size_t)(r0 + (ty << 3) + i) * NG + g0 + (tx << 3);
        float4 o0 = {acc[i][0]+bv[0], acc[i][1]+bv[1], acc[i][2]+bv[2], acc[i][3]+bv[3]};
        float4 o1 = {acc[i][4]+bv[4], acc[i][5]+bv[5], acc[i][6]+bv[6], acc[i][7]+bv[7]};
        *(float4*)orow = o0;
        *(float4*)(orow + 4) = o1;
    }
}

// ---------------------------------------------------------------------------
// Register-resident LSTM recurrence. 2 blocks per chain (s=0: u 0..127,
// s=1: u 128..255), 512 threads. Thread (vq=tid>>7, u=tid&127) computes
// 4 gates of hidden unit (s*128+u) over v in [vq*64, vq*64+64).
// Weights: 48 float4 in VGPRs + 16 float4 in LDS per thread.
// Cross-block h exchange per step through hs[] + release/acquire flags.
// ---------------------------------------------------------------------------
#define DOT_STEP(J, HV) { \
    float4 h4 = (HV); \
    float4 w0 = ((J) < 12) ? wr[(J)]      : lds_w[((J)-12)*512 + tid]; \
    float4 w1 = ((J) < 12) ? wr[12+(J)]   : lds_w[(4+(J)-12)*512 + tid]; \
    float4 w2 = ((J) < 12) ? wr[24+(J)]   : lds_w[(8+(J)-12)*512 + tid]; \
    float4 w3 = ((J) < 12) ? wr[36+(J)]   : lds_w[(12+(J)-12)*512 + tid]; \
    acc0.x += w0.x*h4.x; acc0.y += w0.y*h4.y; acc0.z += w0.z*h4.z; acc0.w += w0.w*h4.w; \
    acc1.x += w1.x*h4.x; acc1.y += w1.y*h4.y; acc1.z += w1.z*h4.z; acc1.w += w1.w*h4.w; \
    acc2.x += w2.x*h4.x; acc2.y += w2.y*h4.y; acc2.z += w2.z*h4.z; acc2.w += w2.w*h4.w; \
    acc3.x += w3.x*h4.x; acc3.y += w3.y*h4.y; acc3.z += w3.z*h4.z; acc3.w += w3.w*h4.w; }

__global__ __launch_bounds__(512, 2)
void k_lstm2(const float* __restrict__ xpF, const float* __restrict__ xpB,
             const float* __restrict__ ww, const int* __restrict__ lengths,
             float* hs, int* flags, int chainBase, int nchains) {
    int cl = blockIdx.x % nchains;
    int s  = blockIdx.x / nchains;
    int c  = chainBase + cl;
    int dir = c >> 6;
    int b   = c & 63;
    const float* xp = dir ? xpB : xpF;

    int tid = threadIdx.x;
    int vq = tid >> 7;
    int u  = tid & 127;
    bool own = (vq >> 1) == s;
    int len = lengths[b];

    __shared__ float4 lds_w[16 * 512];          // 128 KB
    __shared__ __align__(16) float lds_h[2][128];
    __shared__ float4 lds_part[512];            // 8 KB

    const float4* wwp = (const float4*)ww;
    size_t wbase = ((((size_t)(dir * 2 + s) * 4 + vq) * 128) + u) * 64;
    float4 wr[48];
    #pragma unroll
    for (int k = 0; k < 4; ++k)
        #pragma unroll
        for (int j = 0; j < 12; ++j)
            wr[k * 12 + j] = wwp[wbase + k * 16 + j];
    #pragma unroll
    for (int k = 0; k < 4; ++k)
        #pragma unroll
        for (int j = 0; j < 4; ++j)
            lds_w[(k * 4 + j) * 512 + tid] = wwp[wbase + k * 16 + 12 + j];

    if (tid < 128) { lds_h[0][tid] = 0.f; lds_h[1][tid] = 0.f; }
    float c_state = 0.f;
    __syncthreads();

    float* hsrow = hs + (size_t)c * NT * NH;    // hs[c][t][256]
    int* flSelf = flags + ((c * 2 + s) << 9);
    int* flPart = flags + ((c * 2 + (1 - s)) << 9);

    int cur = 0;
    for (int tt = 0; tt < NT; ++tt) {
        int t = dir ? (NT - 1 - tt) : tt;
        bool active = (t < len);

        float x0 = 0.f, x1 = 0.f, x2 = 0.f, x3 = 0.f;
        if (tid < 128) {   // prefetch xp for the update phase
            const float* xr = xp + ((size_t)b * NT + t) * NG + s * 128 + u;
            x0 = xr[0]; x1 = xr[256]; x2 = xr[512]; x3 = xr[768];
        }

        float4 acc0 = {0.f,0.f,0.f,0.f}, acc1 = acc0, acc2 = acc0, acc3 = acc0;
        if (active && tt > 0) {
            if (own) {
                const int hoff = (vq & 1) * 64;
                #pragma unroll
                for (int j = 0; j < 16; ++j)
                    DOT_STEP(j, *(const float4*)(&lds_h[cur][hoff + j * 4]));
            } else {
                int t_prev = dir ? (t + 1) : (t - 1);
                const int* fp = flPart + (tt - 1);
                while (__hip_atomic_load(fp, __ATOMIC_ACQUIRE,
                                         __HIP_MEMORY_SCOPE_AGENT) == 0) {}
                const float4* hg = (const float4*)(hsrow + (size_t)t_prev * NH + vq * 64);
                #pragma unroll
                for (int j = 0; j < 16; ++j)
                    DOT_STEP(j, hg[j]);
            }
        }
        float4 pw;
        pw.x = acc0.x + acc0.y + acc0.z + acc0.w;
        pw.y = acc1.x + acc1.y + acc1.z + acc1.w;
        pw.z = acc2.x + acc2.y + acc2.z + acc2.w;
        pw.w = acc3.x + acc3.y + acc3.z + acc3.w;
        lds_part[vq * 128 + u] = pw;
        __syncthreads();

        if (tid < 128) {
            float4 g0 = lds_part[u], g1 = lds_part[128 + u];
            float4 g2 = lds_part[256 + u], g3 = lds_part[384 + u];
            float pi = g0.x + g1.x + g2.x + g3.x + x0;
            float pf = g0.y + g1.y + g2.y + g3.y + x1;
            float pg = g0.z + g1.z + g2.z + g3.z + x2;
            float po = g0.w + g1.w + g2.w + g3.w + x3;
            float h_old = lds_h[cur][u];
            float hv;
            if (active) {
                float gi = sigf(pi), gf = sigf(pf), gg = tanhf(pg), go = sigf(po);
                c_state = gf * c_state + gi * gg;
                hv = go * tanhf(c_state);
            } else {
                hv = h_old;
            }
            lds_h[cur ^ 1][u] = hv;
            hsrow[(size_t)t * NH + s * 128 + u] = hv;
        }
        __syncthreads();
        if (tid == 0) {
            __threadfence();
            __hip_atomic_store(flSelf + tt, 1, __ATOMIC_RELEASE,
                               __HIP_MEMORY_SCOPE_AGENT);
        }
        cur ^= 1;
    }
}

// ---------------------------------------------------------------------------
// Classifier GEMM: logits[r][kk] = sum_j concat(hsF,hsB)[r][j]*W_clf[kk][j]+b
// 128-row tile per block, W_clf staged transposed in LDS.
// ---------------------------------------------------------------------------
__global__ __launch_bounds__(256, 4)
void k_clf(const float* __restrict__ hsF, const float* __restrict__ hsB,
           const float* __restrict__ Wclf, const float* __restrict__ bclf,
           float* __restrict__ logits) {
    __shared__ float wt[512 * 32];   // 64 KB  [j][kk]
    __shared__ float xt[32 * 128];   // 16 KB  [j'][r]
    int tid = threadIdx.x;
    int r0 = blockIdx.x << 7;
    // stage W transposed
    #pragma unroll
    for (int e = 0; e < 64; ++e) {
        int idx = e * 256 + tid;           // flat over [32][512]
        int kk = idx >> 9, j = idx & 511;
        wt[j * 32 + kk] = Wclf[idx];
    }
    int rl = tid >> 1, half = tid & 1;
    int kk = tid & 31, rg = tid >> 5;
    float acc[16] = {};
    for (int jc = 0; jc < 16; ++jc) {
        const float* src = (jc < 8 ? hsF : hsB) +
                           (size_t)(r0 + rl) * NH + ((jc & 7) << 5) + (half << 4);
        float4 v0 = *(const float4*)(src + 0);
        float4 v1 = *(const float4*)(src + 4);
        float4 v2 = *(const float4*)(src + 8);
        float4 v3 = *(const float4*)(src + 12);
        __syncthreads();   // previous chunk's compute done
        int jb = half << 4;
        xt[(jb+ 0)*128 + rl] = v0.x; xt[(jb+ 1)*128 + rl] = v0.y;
        xt[(jb+ 2)*128 + rl] = v0.z; xt[(jb+ 3)*128 + rl] = v0.w;
        xt[(jb+ 4)*128 + rl] = v1.x; xt[(jb+ 5)*128 + rl] = v1.y;
        xt[(jb+ 6)*128 + rl] = v1.z; xt[(jb+ 7)*128 + rl] = v1.w;
        xt[(jb+ 8)*128 + rl] = v2.x; xt[(jb+ 9)*128 + rl] = v2.y;
        xt[(jb+10)*128 + rl] = v2.z; xt[(jb+11)*128 + rl] = v2.w;
        xt[(jb+12)*128 + rl] = v3.x; xt[(jb+13)*128 + rl] = v3.y;
        xt[(jb+14)*128 + rl] = v3.z; xt[(jb+15)*128 + rl] = v3.w;
        __syncthreads();
        #pragma unroll
        for (int jp = 0; jp < 32; ++jp) {
            float w = wt[(jc * 32 + jp) * 32 + kk];
            const float* xr = &xt[jp * 128 + rg * 16];
            float4 x0 = *(const float4*)(xr + 0);
            float4 x1 = *(const float4*)(xr + 4);
            float4 x2 = *(const float4*)(xr + 8);
            float4 x3 = *(const float4*)(xr + 12);
            acc[ 0] += x0.x*w; acc[ 1] += x0.y*w; acc[ 2] += x0.z*w; acc[ 3] += x0.w*w;
            acc[ 4] += x1.x*w; acc[ 5] += x1.y*w; acc[ 6] += x1.z*w; acc[ 7] += x1.w*w;
            acc[ 8] += x2.x*w; acc[ 9] += x2.y*w; acc[10] += x2.z*w; acc[11] += x2.w*w;
            acc[12] += x3.x*w; acc[13] += x3.y*w; acc[14] += x3.z*w; acc[15] += x3.w*w;
        }
    }
    float bb = bclf[kk];
    #pragma unroll
    for (int i = 0; i < 16; ++i)
        logits[(size_t)(r0 + rg * 16 + i) * NK + kk] = acc[i] + bb;
}

// ---------------------------------------------------------------------------
// Viterbi (unchanged): one wave per batch, ref-exact rounding order
// ---------------------------------------------------------------------------
__global__ __launch_bounds__(64)
void k_viterbi(const float* __restrict__ logits, const int* __restrict__ lengths,
               const float* __restrict__ st, const float* __restrict__ et,
               const float* __restrict__ trans, float* __restrict__ preds) {
    int b = blockIdx.x, lane = threadIdx.x;
    __shared__ unsigned char hist[NT - 1][NK];
    int len = lengths[b];
    int k = lane & 31;
    float wt[32];
    #pragma unroll
    for (int j = 0; j < 32; ++j) wt[j] = trans[j * NK + k];
    const float* lg = logits + (size_t)b * NT * NK;
    float score = st[k] + lg[k];
    for (int t = 1; t < NT; ++t) {
        float emis = lg[t * NK + k];
        float best = -3.4e38f; int bidx = 0;
        #pragma unroll
        for (int j = 0; j < 32; ++j) {
            float cand = (__shfl(score, j, 64) + wt[j]) + emis;
            if (cand > best) { best = cand; bidx = j; }
        }
        bool m = t < len;
        if (lane < 32) hist[t - 1][k] = (unsigned char)(m ? bidx : k);
        score = m ? best : score;
    }
    score += et[k];
    float bv = -3.4e38f; int btag = 0;
    #pragma unroll
    for (int j = 0; j < 32; ++j) {
        float v = __shfl(score, j, 64);
        if (v > bv) { bv = v; btag = j; }
    }
    __syncthreads();
    if (lane == 0) {
        int tag = btag;
        for (int t = NT - 1; t >= 1; --t) {
            preds[(size_t)b * NT + t] = (t < len) ? (float)tag : 0.f;
            tag = hist[t - 1][tag];
        }
        preds[(size_t)b * NT] = (float)tag;
    }
}

// ---------------------------------------------------------------------------
extern "C" void kernel_launch(void* const* d_in, const int* in_sizes, int n_in,
                              void* d_out, int out_size, void* d_ws, size_t ws_size,
                              hipStream_t stream) {
    (void)in_sizes; (void)n_in; (void)out_size;
    const float* x       = (const float*)d_in[0];
    const int*   lengths = (const int*)d_in[1];
    const float* Wih_f = (const float*)d_in[3];
    const float* Whh_f = (const float*)d_in[4];
    const float* b_f   = (const float*)d_in[5];
    const float* Wih_b = (const float*)d_in[6];
    const float* Whh_b = (const float*)d_in[7];
    const float* b_b   = (const float*)d_in[8];
    const float* W_clf = (const float*)d_in[9];
    const float* b_clf = (const float*)d_in[10];
    const float* st    = (const float*)d_in[11];
    const float* et    = (const float*)d_in[12];
    const float* trans = (const float*)d_in[13];

    float* logits = (float*)d_out;
    float* preds  = logits + (size_t)NBT * NK;

    const size_t XPB = (size_t)NBT * NG * 4;          // 134,217,728
    const size_t HSB = (size_t)2 * NB * NT * NH * 4;  //  67,108,864
    const size_t WWB = (size_t)524288 * 4;            //   2,097,152
    const size_t FLB = (size_t)128 * 2 * 512 * 4;     //     524,288
    bool conc = ws_size >= 2 * XPB + HSB + WWB + FLB;

    char* ws = (char*)d_ws;
    float* xp0 = (float*)ws;
    float* xp1 = conc ? (float*)(ws + XPB) : xp0;
    char*  rest = ws + (conc ? 2 : 1) * XPB;
    float* hsbuf = (float*)rest;
    float* hsF = hsbuf;
    float* hsB = hsbuf + (size_t)NB * NT * NH;
    float* wwp = (float*)(rest + HSB);
    int*   flg = (int*)(rest + HSB + WWB);

    hipMemsetAsync(flg, 0, FLB, stream);
    k_wprep2<<<2048, 256, 0, stream>>>(Whh_f, Whh_b, wwp);

    if (conc) {
        k_gemm_f<<<dim3(16, 256), 256, 0, stream>>>(x, Wih_f, Wih_b, b_f, b_b,
                                                    xp0, xp1, 0);
        k_lstm2<<<256, 512, 0, stream>>>(xp0, xp1, wwp, lengths, hsbuf, flg, 0, 128);
    } else {
        k_gemm_f<<<dim3(8, 256), 256, 0, stream>>>(x, Wih_f, Wih_b, b_f, b_b,
                                                   xp0, xp0, 0);
        k_lstm2<<<128, 512, 0, stream>>>(xp0, xp0, wwp, lengths, hsbuf, flg, 0, 64);
        k_gemm_f<<<dim3(8, 256), 256, 0, stream>>>(x, Wih_f, Wih_b, b_f, b_b,
                                                   xp0, xp0, 8);
        k_lstm2<<<128, 512, 0, stream>>>(xp0, xp0, wwp, lengths, hsbuf, flg, 64, 64);
    }
    k_clf<<<256, 256, 0, stream>>>(hsF, hsB, W_clf, b_clf, logits);
    k_viterbi<<<NB, 64, 0, stream>>>(logits, lengths, st, et, trans, preds);
}

// Round 3
// 12883.739 us; speedup vs baseline: 1.1321x; 1.1321x over previous
//
#include <hip/hip_runtime.h>
#include <math.h>

#define NB 64
#define NT 512
#define ND 512
#define NH 256
#define NG 1024   // 4*H
#define NK 32
#define NBT (NB*NT)

__device__ __forceinline__ float sigf(float x) { return 1.f / (1.f + expf(-x)); }

// ---------------------------------------------------------------------------
// Weight prep: ww[(((dir*2+s)*4+vq)*128+u)*64 + k*16 + j4][e] =
//              Whh_dir[(k*256 + s*128 + u)*256 + (vq*64 + j4*4 + e)]
// ---------------------------------------------------------------------------
__global__ void k_wprep2(const float* __restrict__ Wf, const float* __restrict__ Wb,
                         float* __restrict__ ww) {
    int f = blockIdx.x * 256 + threadIdx.x;      // 0 .. 524287
    int e   = f & 3;
    int j4  = (f >> 2) & 15;
    int k   = (f >> 6) & 3;
    int u   = (f >> 8) & 127;
    int vq  = (f >> 15) & 3;
    int s   = (f >> 17) & 1;
    int dir = f >> 18;
    const float* W = dir ? Wb : Wf;
    ww[f] = W[(size_t)(k * 256 + s * 128 + u) * 256 + (vq * 64 + j4 * 4 + e)];
}

// ---------------------------------------------------------------------------
// Fused input projection GEMM (both dirs): xp_dir = x @ Wih_dir^T + b_dir
// 128x128 tile, 8x8 per thread, K-chunks of 16.
// ---------------------------------------------------------------------------
__global__ __launch_bounds__(256, 4)
void k_gemm_f(const float* __restrict__ x, const float* __restrict__ Wf,
              const float* __restrict__ Wb, const float* __restrict__ bf,
              const float* __restrict__ bb, float* __restrict__ xpF,
              float* __restrict__ xpB, int bxBase) {
    __shared__ float As[16][132];
    __shared__ float Bs[16][132];
    int tid = threadIdx.x;
    int bx = blockIdx.x + bxBase;
    int dir = bx >> 3;
    const float* W    = dir ? Wb : Wf;
    const float* bias = dir ? bb : bf;
    float* xp         = dir ? xpB : xpF;
    int r0 = blockIdx.y << 7;
    int g0 = (bx & 7) << 7;
    int rl = tid >> 1, k8 = (tid & 1) << 3;
    const float* xa = x + (size_t)(r0 + rl) * ND + k8;
    const float* wa = W + (size_t)(g0 + rl) * ND + k8;
    int tx = tid & 15, ty = tid >> 4;
    float acc[8][8] = {};
    for (int kt = 0; kt < ND; kt += 16) {
        float4 a0 = *(const float4*)(xa + kt);
        float4 a1 = *(const float4*)(xa + kt + 4);
        float4 w0 = *(const float4*)(wa + kt);
        float4 w1 = *(const float4*)(wa + kt + 4);
        As[k8+0][rl]=a0.x; As[k8+1][rl]=a0.y; As[k8+2][rl]=a0.z; As[k8+3][rl]=a0.w;
        As[k8+4][rl]=a1.x; As[k8+5][rl]=a1.y; As[k8+6][rl]=a1.z; As[k8+7][rl]=a1.w;
        Bs[k8+0][rl]=w0.x; Bs[k8+1][rl]=w0.y; Bs[k8+2][rl]=w0.z; Bs[k8+3][rl]=w0.w;
        Bs[k8+4][rl]=w1.x; Bs[k8+5][rl]=w1.y; Bs[k8+6][rl]=w1.z; Bs[k8+7][rl]=w1.w;
        __syncthreads();
        #pragma unroll
        for (int kk = 0; kk < 16; ++kk) {
            float4 av0 = *(const float4*)(&As[kk][ty << 3]);
            float4 av1 = *(const float4*)(&As[kk][(ty << 3) + 4]);
            float4 bv0 = *(const float4*)(&Bs[kk][tx << 3]);
            float4 bv1 = *(const float4*)(&Bs[kk][(tx << 3) + 4]);
            float aa[8] = {av0.x, av0.y, av0.z, av0.w, av1.x, av1.y, av1.z, av1.w};
            float bbv[8] = {bv0.x, bv0.y, bv0.z, bv0.w, bv1.x, bv1.y, bv1.z, bv1.w};
            #pragma unroll
            for (int i = 0; i < 8; ++i)
                #pragma unroll
                for (int j = 0; j < 8; ++j)
                    acc[i][j] += aa[i] * bbv[j];
        }
        __syncthreads();
    }
    float bv[8];
    #pragma unroll
    for (int j = 0; j < 8; ++j) bv[j] = bias[g0 + (tx << 3) + j];
    #pragma unroll
    for (int i = 0; i < 8; ++i) {
        float* orow = xp + (size_t)(r0 + (ty << 3) + i) * NG + g0 + (tx << 3);
        float4 o0 = {acc[i][0]+bv[0], acc[i][1]+bv[1], acc[i][2]+bv[2], acc[i][3]+bv[3]};
        float4 o1 = {acc[i][4]+bv[4], acc[i][5]+bv[5], acc[i][6]+bv[6], acc[i][7]+bv[7]};
        *(float4*)orow = o0;
        *(float4*)(orow + 4) = o1;
    }
}

// ---------------------------------------------------------------------------
// Register-resident LSTM recurrence. 2 blocks per chain (s=0: u 0..127,
// s=1: u 128..255), 512 threads, 1 block/CU (launch_bounds(512,1) -> 256 VGPR
// cap, weights stay resident: 48 float4 in VGPRs + 16 float4 in LDS).
// h history written to hs (row stride hstr); in conc mode hs aliases the
// gate-i columns of xp (each thread writes the exact element it already read).
// Cross-block h exchange per step through hs + release/acquire flags.
// Blocks (cl, cl+nchains) pair same-XCD under round-robin dispatch.
// ---------------------------------------------------------------------------
#define DOT_STEP(J, HV) { \
    float4 h4 = (HV); \
    float4 w0 = ((J) < 12) ? wr[(J)]      : lds_w[((J)-12)*512 + tid]; \
    float4 w1 = ((J) < 12) ? wr[12+(J)]   : lds_w[(4+(J)-12)*512 + tid]; \
    float4 w2 = ((J) < 12) ? wr[24+(J)]   : lds_w[(8+(J)-12)*512 + tid]; \
    float4 w3 = ((J) < 12) ? wr[36+(J)]   : lds_w[(12+(J)-12)*512 + tid]; \
    acc0.x += w0.x*h4.x; acc0.y += w0.y*h4.y; acc0.z += w0.z*h4.z; acc0.w += w0.w*h4.w; \
    acc1.x += w1.x*h4.x; acc1.y += w1.y*h4.y; acc1.z += w1.z*h4.z; acc1.w += w1.w*h4.w; \
    acc2.x += w2.x*h4.x; acc2.y += w2.y*h4.y; acc2.z += w2.z*h4.z; acc2.w += w2.w*h4.w; \
    acc3.x += w3.x*h4.x; acc3.y += w3.y*h4.y; acc3.z += w3.z*h4.z; acc3.w += w3.w*h4.w; }

__global__ __launch_bounds__(512, 1)
void k_lstm2(const float* __restrict__ xpF, const float* __restrict__ xpB,
             const float* __restrict__ ww, const int* __restrict__ lengths,
             float* hsF, float* hsB, int hstr,
             int* flags, int chainBase, int nchains) {
    int cl = blockIdx.x % nchains;
    int s  = blockIdx.x / nchains;
    int c  = chainBase + cl;
    int dir = c >> 6;
    int b   = c & 63;
    const float* xp = dir ? xpB : xpF;
    float* hsD      = dir ? hsB : hsF;

    int tid = threadIdx.x;
    int vq = tid >> 7;
    int u  = tid & 127;
    bool own = (vq >> 1) == s;
    int len = lengths[b];

    __shared__ float4 lds_w[16 * 512];          // 128 KB
    __shared__ __align__(16) float lds_h[2][128];
    __shared__ float4 lds_part[512];            // 8 KB

    const float4* wwp = (const float4*)ww;
    size_t wbase = ((((size_t)(dir * 2 + s) * 4 + vq) * 128) + u) * 64;
    float4 wr[48];
    #pragma unroll
    for (int k = 0; k < 4; ++k)
        #pragma unroll
        for (int j = 0; j < 12; ++j)
            wr[k * 12 + j] = wwp[wbase + k * 16 + j];
    #pragma unroll
    for (int k = 0; k < 4; ++k)
        #pragma unroll
        for (int j = 0; j < 4; ++j)
            lds_w[(k * 4 + j) * 512 + tid] = wwp[wbase + k * 16 + 12 + j];

    if (tid < 128) { lds_h[0][tid] = 0.f; lds_h[1][tid] = 0.f; }
    float c_state = 0.f;
    __syncthreads();

    float* hbase = hsD + (size_t)b * NT * hstr;
    int* flSelf = flags + ((c * 2 + s) << 9);
    int* flPart = flags + ((c * 2 + (1 - s)) << 9);

    int cur = 0;
    for (int tt = 0; tt < NT; ++tt) {
        int t = dir ? (NT - 1 - tt) : tt;
        bool active = (t < len);

        float x0 = 0.f, x1 = 0.f, x2 = 0.f, x3 = 0.f;
        if (tid < 128) {   // prefetch xp for the update phase (incl. gate-i col we later overwrite)
            const float* xr = xp + ((size_t)b * NT + t) * NG + s * 128 + u;
            x0 = xr[0]; x1 = xr[256]; x2 = xr[512]; x3 = xr[768];
        }

        float4 acc0 = {0.f,0.f,0.f,0.f}, acc1 = acc0, acc2 = acc0, acc3 = acc0;
        if (active && tt > 0) {
            if (own) {
                const int hoff = (vq & 1) * 64;
                #pragma unroll
                for (int j = 0; j < 16; ++j)
                    DOT_STEP(j, *(const float4*)(&lds_h[cur][hoff + j * 4]));
            } else {
                int t_prev = dir ? (t + 1) : (t - 1);
                const int* fp = flPart + (tt - 1);
                while (__hip_atomic_load(fp, __ATOMIC_ACQUIRE,
                                         __HIP_MEMORY_SCOPE_AGENT) == 0) {}
                const float4* hg = (const float4*)(hbase + (size_t)t_prev * hstr + vq * 64);
                #pragma unroll
                for (int j = 0; j < 16; ++j)
                    DOT_STEP(j, hg[j]);
            }
        }
        float4 pw;
        pw.x = acc0.x + acc0.y + acc0.z + acc0.w;
        pw.y = acc1.x + acc1.y + acc1.z + acc1.w;
        pw.z = acc2.x + acc2.y + acc2.z + acc2.w;
        pw.w = acc3.x + acc3.y + acc3.z + acc3.w;
        lds_part[vq * 128 + u] = pw;
        __syncthreads();

        if (tid < 128) {
            float4 g0 = lds_part[u], g1 = lds_part[128 + u];
            float4 g2 = lds_part[256 + u], g3 = lds_part[384 + u];
            float pi = g0.x + g1.x + g2.x + g3.x + x0;
            float pf = g0.y + g1.y + g2.y + g3.y + x1;
            float pg = g0.z + g1.z + g2.z + g3.z + x2;
            float po = g0.w + g1.w + g2.w + g3.w + x3;
            float h_old = lds_h[cur][u];
            float hv;
            if (active) {
                float gi = sigf(pi), gf = sigf(pf), gg = tanhf(pg), go = sigf(po);
                c_state = gf * c_state + gi * gg;
                hv = go * tanhf(c_state);
            } else {
                hv = h_old;
            }
            lds_h[cur ^ 1][u] = hv;
            hbase[(size_t)t * hstr + s * 128 + u] = hv;
        }
        __syncthreads();   // drains vmcnt -> h visible at L2 before flag release
        if (tid == 0)
            __hip_atomic_store(flSelf + tt, 1, __ATOMIC_RELEASE,
                               __HIP_MEMORY_SCOPE_AGENT);
        cur ^= 1;
    }
}

// ---------------------------------------------------------------------------
// Classifier GEMM: logits[r][kk] = sum_j concat(hsF,hsB)[r][j]*W_clf[kk][j]+b
// hs rows have stride hstr (1024 when aliased into xp, 256 standalone).
// ---------------------------------------------------------------------------
__global__ __launch_bounds__(256, 4)
void k_clf(const float* __restrict__ hsF, const float* __restrict__ hsB,
           int hstr, const float* __restrict__ Wclf, const float* __restrict__ bclf,
           float* __restrict__ logits) {
    __shared__ float wt[512 * 32];   // 64 KB  [j][kk]
    __shared__ float xt[32 * 128];   // 16 KB  [j'][r]
    int tid = threadIdx.x;
    int r0 = blockIdx.x << 7;
    #pragma unroll
    for (int e = 0; e < 64; ++e) {
        int idx = e * 256 + tid;           // flat over [32][512]
        int kk = idx >> 9, j = idx & 511;
        wt[j * 32 + kk] = Wclf[idx];
    }
    int rl = tid >> 1, half = tid & 1;
    int kk = tid & 31, rg = tid >> 5;
    float acc[16] = {};
    for (int jc = 0; jc < 16; ++jc) {
        const float* src = (jc < 8 ? hsF : hsB) +
                           (size_t)(r0 + rl) * hstr + ((jc & 7) << 5) + (half << 4);
        float4 v0 = *(const float4*)(src + 0);
        float4 v1 = *(const float4*)(src + 4);
        float4 v2 = *(const float4*)(src + 8);
        float4 v3 = *(const float4*)(src + 12);
        __syncthreads();
        int jb = half << 4;
        xt[(jb+ 0)*128 + rl] = v0.x; xt[(jb+ 1)*128 + rl] = v0.y;
        xt[(jb+ 2)*128 + rl] = v0.z; xt[(jb+ 3)*128 + rl] = v0.w;
        xt[(jb+ 4)*128 + rl] = v1.x; xt[(jb+ 5)*128 + rl] = v1.y;
        xt[(jb+ 6)*128 + rl] = v1.z; xt[(jb+ 7)*128 + rl] = v1.w;
        xt[(jb+ 8)*128 + rl] = v2.x; xt[(jb+ 9)*128 + rl] = v2.y;
        xt[(jb+10)*128 + rl] = v2.z; xt[(jb+11)*128 + rl] = v2.w;
        xt[(jb+12)*128 + rl] = v3.x; xt[(jb+13)*128 + rl] = v3.y;
        xt[(jb+14)*128 + rl] = v3.z; xt[(jb+15)*128 + rl] = v3.w;
        __syncthreads();
        #pragma unroll
        for (int jp = 0; jp < 32; ++jp) {
            float w = wt[(jc * 32 + jp) * 32 + kk];
            const float* xr = &xt[jp * 128 + rg * 16];
            float4 x0 = *(const float4*)(xr + 0);
            float4 x1 = *(const float4*)(xr + 4);
            float4 x2 = *(const float4*)(xr + 8);
            float4 x3 = *(const float4*)(xr + 12);
            acc[ 0] += x0.x*w; acc[ 1] += x0.y*w; acc[ 2] += x0.z*w; acc[ 3] += x0.w*w;
            acc[ 4] += x1.x*w; acc[ 5] += x1.y*w; acc[ 6] += x1.z*w; acc[ 7] += x1.w*w;
            acc[ 8] += x2.x*w; acc[ 9] += x2.y*w; acc[10] += x2.z*w; acc[11] += x2.w*w;
            acc[12] += x3.x*w; acc[13] += x3.y*w; acc[14] += x3.z*w; acc[15] += x3.w*w;
        }
    }
    float bb = bclf[kk];
    #pragma unroll
    for (int i = 0; i < 16; ++i)
        logits[(size_t)(r0 + rg * 16 + i) * NK + kk] = acc[i] + bb;
}

// ---------------------------------------------------------------------------
// Viterbi: one wave per batch, ref-exact rounding order
// ---------------------------------------------------------------------------
__global__ __launch_bounds__(64)
void k_viterbi(const float* __restrict__ logits, const int* __restrict__ lengths,
               const float* __restrict__ st, const float* __restrict__ et,
               const float* __restrict__ trans, float* __restrict__ preds) {
    int b = blockIdx.x, lane = threadIdx.x;
    __shared__ unsigned char hist[NT - 1][NK];
    int len = lengths[b];
    int k = lane & 31;
    float wt[32];
    #pragma unroll
    for (int j = 0; j < 32; ++j) wt[j] = trans[j * NK + k];
    const float* lg = logits + (size_t)b * NT * NK;
    float score = st[k] + lg[k];
    for (int t = 1; t < NT; ++t) {
        float emis = lg[t * NK + k];
        float best = -3.4e38f; int bidx = 0;
        #pragma unroll
        for (int j = 0; j < 32; ++j) {
            float cand = (__shfl(score, j, 64) + wt[j]) + emis;
            if (cand > best) { best = cand; bidx = j; }
        }
        bool m = t < len;
        if (lane < 32) hist[t - 1][k] = (unsigned char)(m ? bidx : k);
        score = m ? best : score;
    }
    score += et[k];
    float bv = -3.4e38f; int btag = 0;
    #pragma unroll
    for (int j = 0; j < 32; ++j) {
        float v = __shfl(score, j, 64);
        if (v > bv) { bv = v; btag = j; }
    }
    __syncthreads();
    if (lane == 0) {
        int tag = btag;
        for (int t = NT - 1; t >= 1; --t) {
            preds[(size_t)b * NT + t] = (t < len) ? (float)tag : 0.f;
            tag = hist[t - 1][tag];
        }
        preds[(size_t)b * NT] = (float)tag;
    }
}

// ---------------------------------------------------------------------------
extern "C" void kernel_launch(void* const* d_in, const int* in_sizes, int n_in,
                              void* d_out, int out_size, void* d_ws, size_t ws_size,
                              hipStream_t stream) {
    (void)in_sizes; (void)n_in; (void)out_size;
    const float* x       = (const float*)d_in[0];
    const int*   lengths = (const int*)d_in[1];
    const float* Wih_f = (const float*)d_in[3];
    const float* Whh_f = (const float*)d_in[4];
    const float* b_f   = (const float*)d_in[5];
    const float* Wih_b = (const float*)d_in[6];
    const float* Whh_b = (const float*)d_in[7];
    const float* b_b   = (const float*)d_in[8];
    const float* W_clf = (const float*)d_in[9];
    const float* b_clf = (const float*)d_in[10];
    const float* st    = (const float*)d_in[11];
    const float* et    = (const float*)d_in[12];
    const float* trans = (const float*)d_in[13];

    float* logits = (float*)d_out;
    float* preds  = logits + (size_t)NBT * NK;

    const size_t XPB = (size_t)NBT * NG * 4;          // 134,217,728
    const size_t HSB = (size_t)2 * NB * NT * NH * 4;  //  67,108,864 (serial only)
    const size_t WWB = (size_t)524288 * 4;            //   2,097,152
    const size_t FLB = (size_t)128 * 2 * 512 * 4;     //     524,288
    bool conc = ws_size >= 2 * XPB + WWB + FLB;       // 271 MB (hs aliased into xp)

    char* ws = (char*)d_ws;
    float* xp0 = (float*)ws;
    float* xp1 = conc ? (float*)(ws + XPB) : xp0;
    char*  rest = ws + (conc ? 2 : 1) * XPB;
    float *hsF, *hsB, *wwp; int* flg; int hstr;
    if (conc) {
        hsF = xp0; hsB = xp1; hstr = NG;              // alias gate-i columns
        wwp = (float*)rest;
        flg = (int*)(rest + WWB);
    } else {
        hsF = (float*)rest; hsB = hsF + (size_t)NB * NT * NH; hstr = NH;
        wwp = (float*)(rest + HSB);
        flg = (int*)(rest + HSB + WWB);
    }

    hipMemsetAsync(flg, 0, FLB, stream);
    k_wprep2<<<2048, 256, 0, stream>>>(Whh_f, Whh_b, wwp);

    if (conc) {
        k_gemm_f<<<dim3(16, 256), 256, 0, stream>>>(x, Wih_f, Wih_b, b_f, b_b,
                                                    xp0, xp1, 0);
        k_lstm2<<<256, 512, 0, stream>>>(xp0, xp1, wwp, lengths,
                                         hsF, hsB, hstr, flg, 0, 128);
    } else {
        k_gemm_f<<<dim3(8, 256), 256, 0, stream>>>(x, Wih_f, Wih_b, b_f, b_b,
                                                   xp0, xp0, 0);
        k_lstm2<<<128, 512, 0, stream>>>(xp0, xp0, wwp, lengths,
                                         hsF, hsB, hstr, flg, 0, 64);
        k_gemm_f<<<dim3(8, 256), 256, 0, stream>>>(x, Wih_f, Wih_b, b_f, b_b,
                                                   xp0, xp0, 8);
        k_lstm2<<<128, 512, 0, stream>>>(xp0, xp0, wwp, lengths,
                                         hsF, hsB, hstr, flg, 64, 64);
    }
    k_clf<<<256, 256, 0, stream>>>(hsF, hsB, hstr, W_clf, b_clf, logits);
    k_viterbi<<<NB, 64, 0, stream>>>(logits, lengths, st, et, trans, preds);
}

// Round 4
// 9309.583 us; speedup vs baseline: 1.5667x; 1.3839x over previous
//
#include <hip/hip_runtime.h>
#include <math.h>

#define NB 64
#define NT 512
#define ND 512
#define NH 256
#define NG 1024   // 4*H
#define NK 32
#define NBT (NB*NT)

__device__ __forceinline__ float sigf(float x) { return 1.f / (1.f + expf(-x)); }

// ---------------------------------------------------------------------------
// Weight prep: ww[(((dir*2+s)*4+vq)*128+u)*64 + g*16 + j4][e] =
//              Whh_dir[(g*256 + s*128 + u)*256 + (vq*64 + j4*4 + e)]
// ---------------------------------------------------------------------------
__global__ void k_wprep2(const float* __restrict__ Wf, const float* __restrict__ Wb,
                         float* __restrict__ ww) {
    int f = blockIdx.x * 256 + threadIdx.x;      // 0 .. 524287
    int e   = f & 3;
    int j4  = (f >> 2) & 15;
    int g   = (f >> 6) & 3;
    int u   = (f >> 8) & 127;
    int vq  = (f >> 15) & 3;
    int s   = (f >> 17) & 1;
    int dir = f >> 18;
    const float* W = dir ? Wb : Wf;
    ww[f] = W[(size_t)(g * 256 + s * 128 + u) * 256 + (vq * 64 + j4 * 4 + e)];
}

// ---------------------------------------------------------------------------
// Fused input projection GEMM (both dirs): xp_dir = x @ Wih_dir^T + b_dir
// ---------------------------------------------------------------------------
__global__ __launch_bounds__(256, 4)
void k_gemm_f(const float* __restrict__ x, const float* __restrict__ Wf,
              const float* __restrict__ Wb, const float* __restrict__ bf,
              const float* __restrict__ bb, float* __restrict__ xpF,
              float* __restrict__ xpB, int bxBase) {
    __shared__ float As[16][132];
    __shared__ float Bs[16][132];
    int tid = threadIdx.x;
    int bx = blockIdx.x + bxBase;
    int dir = bx >> 3;
    const float* W    = dir ? Wb : Wf;
    const float* bias = dir ? bb : bf;
    float* xp         = dir ? xpB : xpF;
    int r0 = blockIdx.y << 7;
    int g0 = (bx & 7) << 7;
    int rl = tid >> 1, k8 = (tid & 1) << 3;
    const float* xa = x + (size_t)(r0 + rl) * ND + k8;
    const float* wa = W + (size_t)(g0 + rl) * ND + k8;
    int tx = tid & 15, ty = tid >> 4;
    float acc[8][8] = {};
    for (int kt = 0; kt < ND; kt += 16) {
        float4 a0 = *(const float4*)(xa + kt);
        float4 a1 = *(const float4*)(xa + kt + 4);
        float4 w0 = *(const float4*)(wa + kt);
        float4 w1 = *(const float4*)(wa + kt + 4);
        As[k8+0][rl]=a0.x; As[k8+1][rl]=a0.y; As[k8+2][rl]=a0.z; As[k8+3][rl]=a0.w;
        As[k8+4][rl]=a1.x; As[k8+5][rl]=a1.y; As[k8+6][rl]=a1.z; As[k8+7][rl]=a1.w;
        Bs[k8+0][rl]=w0.x; Bs[k8+1][rl]=w0.y; Bs[k8+2][rl]=w0.z; Bs[k8+3][rl]=w0.w;
        Bs[k8+4][rl]=w1.x; Bs[k8+5][rl]=w1.y; Bs[k8+6][rl]=w1.z; Bs[k8+7][rl]=w1.w;
        __syncthreads();
        #pragma unroll
        for (int kk = 0; kk < 16; ++kk) {
            float4 av0 = *(const float4*)(&As[kk][ty << 3]);
            float4 av1 = *(const float4*)(&As[kk][(ty << 3) + 4]);
            float4 bv0 = *(const float4*)(&Bs[kk][tx << 3]);
            float4 bv1 = *(const float4*)(&Bs[kk][(tx << 3) + 4]);
            float aa[8] = {av0.x, av0.y, av0.z, av0.w, av1.x, av1.y, av1.z, av1.w};
            float bbv[8] = {bv0.x, bv0.y, bv0.z, bv0.w, bv1.x, bv1.y, bv1.z, bv1.w};
            #pragma unroll
            for (int i = 0; i < 8; ++i)
                #pragma unroll
                for (int j = 0; j < 8; ++j)
                    acc[i][j] += aa[i] * bbv[j];
        }
        __syncthreads();
    }
    float bv[8];
    #pragma unroll
    for (int j = 0; j < 8; ++j) bv[j] = bias[g0 + (tx << 3) + j];
    #pragma unroll
    for (int i = 0; i < 8; ++i) {
        float* orow = xp + (size_t)(r0 + (ty << 3) + i) * NG + g0 + (tx << 3);
        float4 o0 = {acc[i][0]+bv[0], acc[i][1]+bv[1], acc[i][2]+bv[2], acc[i][3]+bv[3]};
        float4 o1 = {acc[i][4]+bv[4], acc[i][5]+bv[5], acc[i][6]+bv[6], acc[i][7]+bv[7]};
        *(float4*)orow = o0;
        *(float4*)(orow + 4) = o1;
    }
}

// ---------------------------------------------------------------------------
// Register-resident LSTM recurrence. 2 blocks per chain, 512 threads,
// 1 WG/CU (LDS 137KB). Weights: 48 NAMED float4 in VGPRs (static code only,
// no arrays -> guaranteed promotion) + 16 float4/thread in LDS.
// amdgpu_waves_per_eu(2,2) -> 256-VGPR budget.
// ---------------------------------------------------------------------------
#define FMA4(A, W, H) { (A).x += (W).x*(H).x; (A).y += (W).y*(H).y; \
                        (A).z += (W).z*(H).z; (A).w += (W).w*(H).w; }

#define DECLW1(g,j) float4 w##g##_##j = wwp[wbase + (g)*16 + (j)];
#define DECLWG(g) DECLW1(g,0) DECLW1(g,1) DECLW1(g,2)  DECLW1(g,3) \
                  DECLW1(g,4) DECLW1(g,5) DECLW1(g,6)  DECLW1(g,7) \
                  DECLW1(g,8) DECLW1(g,9) DECLW1(g,10) DECLW1(g,11)

#define DOTR(j, H4) { float4 h4_ = (H4); \
    FMA4(acc0, w0_##j, h4_) FMA4(acc1, w1_##j, h4_) \
    FMA4(acc2, w2_##j, h4_) FMA4(acc3, w3_##j, h4_) }

#define DOTL(j, H4) { float4 h4_ = (H4); \
    float4 l0_ = lds_w[(0*4+(j))*512 + tid]; \
    float4 l1_ = lds_w[(1*4+(j))*512 + tid]; \
    float4 l2_ = lds_w[(2*4+(j))*512 + tid]; \
    float4 l3_ = lds_w[(3*4+(j))*512 + tid]; \
    FMA4(acc0, l0_, h4_) FMA4(acc1, l1_, h4_) \
    FMA4(acc2, l2_, h4_) FMA4(acc3, l3_, h4_) }

#define DOT16(H) \
    DOTR(0,  H(0))  DOTR(1,  H(1))  DOTR(2,  H(2))  DOTR(3,  H(3)) \
    DOTR(4,  H(4))  DOTR(5,  H(5))  DOTR(6,  H(6))  DOTR(7,  H(7)) \
    DOTR(8,  H(8))  DOTR(9,  H(9))  DOTR(10, H(10)) DOTR(11, H(11)) \
    DOTL(0,  H(12)) DOTL(1,  H(13)) DOTL(2,  H(14)) DOTL(3,  H(15))

__global__ void
__attribute__((amdgpu_flat_work_group_size(512, 512)))
__attribute__((amdgpu_waves_per_eu(2, 2)))
k_lstm2(const float* __restrict__ xpF, const float* __restrict__ xpB,
        const float* __restrict__ ww, const int* __restrict__ lengths,
        float* hsF, float* hsB, int hstr,
        int* flags, int chainBase, int nchains) {
    int cl = blockIdx.x % nchains;
    int s  = blockIdx.x / nchains;
    int c  = chainBase + cl;
    int dir = c >> 6;
    int b   = c & 63;
    const float* xp = dir ? xpB : xpF;
    float* hsD      = dir ? hsB : hsF;

    int tid = threadIdx.x;
    int vq = tid >> 7;
    int u  = tid & 127;
    bool own = (vq >> 1) == s;
    int len = lengths[b];

    __shared__ float4 lds_w[16 * 512];          // 128 KB
    __shared__ __align__(16) float lds_h[2][128];
    __shared__ float4 lds_part[512];            // 8 KB

    const float4* wwp = (const float4*)ww;
    size_t wbase = ((((size_t)(dir * 2 + s) * 4 + vq) * 128) + u) * 64;

    DECLWG(0) DECLWG(1) DECLWG(2) DECLWG(3)     // 48 named float4 -> VGPRs

    #pragma unroll
    for (int g = 0; g < 4; ++g)
        #pragma unroll
        for (int j = 0; j < 4; ++j)
            lds_w[(g * 4 + j) * 512 + tid] = wwp[wbase + g * 16 + 12 + j];

    if (tid < 128) { lds_h[0][tid] = 0.f; lds_h[1][tid] = 0.f; }
    float c_state = 0.f;
    __syncthreads();

    float* hbase = hsD + (size_t)b * NT * hstr;
    int* flSelf = flags + ((c * 2 + s) << 9);
    int* flPart = flags + ((c * 2 + (1 - s)) << 9);

    const int hoff = (vq & 1) * 64;
    int cur = 0;
    for (int tt = 0; tt < NT; ++tt) {
        int t = dir ? (NT - 1 - tt) : tt;
        bool active = (t < len);

        float x0 = 0.f, x1 = 0.f, x2 = 0.f, x3 = 0.f;
        if (tid < 128) {   // prefetch xp for the update phase
            const float* xr = xp + ((size_t)b * NT + t) * NG + s * 128 + u;
            x0 = xr[0]; x1 = xr[256]; x2 = xr[512]; x3 = xr[768];
        }

        float4 acc0 = {0.f,0.f,0.f,0.f}, acc1 = acc0, acc2 = acc0, acc3 = acc0;
        if (active && tt > 0) {
            if (own) {
                #define LH(j) (*(const float4*)(&lds_h[cur][hoff + (j)*4]))
                DOT16(LH)
                #undef LH
            } else {
                int t_prev = dir ? (t + 1) : (t - 1);
                const int* fp = flPart + (tt - 1);
                while (__hip_atomic_load(fp, __ATOMIC_ACQUIRE,
                                         __HIP_MEMORY_SCOPE_AGENT) == 0) {}
                const float4* hg = (const float4*)(hbase + (size_t)t_prev * hstr + vq * 64);
                #define GH(j) (hg[(j)])
                DOT16(GH)
                #undef GH
            }
        }
        float4 pw;
        pw.x = acc0.x + acc0.y + acc0.z + acc0.w;
        pw.y = acc1.x + acc1.y + acc1.z + acc1.w;
        pw.z = acc2.x + acc2.y + acc2.z + acc2.w;
        pw.w = acc3.x + acc3.y + acc3.z + acc3.w;
        lds_part[vq * 128 + u] = pw;
        __syncthreads();

        if (tid < 128) {
            float4 g0 = lds_part[u], g1 = lds_part[128 + u];
            float4 g2 = lds_part[256 + u], g3 = lds_part[384 + u];
            float pi = g0.x + g1.x + g2.x + g3.x + x0;
            float pf = g0.y + g1.y + g2.y + g3.y + x1;
            float pg = g0.z + g1.z + g2.z + g3.z + x2;
            float po = g0.w + g1.w + g2.w + g3.w + x3;
            float h_old = lds_h[cur][u];
            float hv;
            if (active) {
                float gi = sigf(pi), gf = sigf(pf), gg = tanhf(pg), go = sigf(po);
                c_state = gf * c_state + gi * gg;
                hv = go * tanhf(c_state);
            } else {
                hv = h_old;
            }
            lds_h[cur ^ 1][u] = hv;
            hbase[(size_t)t * hstr + s * 128 + u] = hv;
        }
        __syncthreads();   // drains vmcnt -> h visible before flag release
        if (tid == 0)
            __hip_atomic_store(flSelf + tt, 1, __ATOMIC_RELEASE,
                               __HIP_MEMORY_SCOPE_AGENT);
        cur ^= 1;
    }
}

// ---------------------------------------------------------------------------
// Classifier GEMM: logits[r][kk] = sum_j concat(hsF,hsB)[r][j]*W_clf[kk][j]+b
// ---------------------------------------------------------------------------
__global__ __launch_bounds__(256, 4)
void k_clf(const float* __restrict__ hsF, const float* __restrict__ hsB,
           int hstr, const float* __restrict__ Wclf, const float* __restrict__ bclf,
           float* __restrict__ logits) {
    __shared__ float wt[512 * 32];   // 64 KB  [j][kk]
    __shared__ float xt[32 * 128];   // 16 KB  [j'][r]
    int tid = threadIdx.x;
    int r0 = blockIdx.x << 7;
    #pragma unroll
    for (int e = 0; e < 64; ++e) {
        int idx = e * 256 + tid;           // flat over [32][512]
        int kk = idx >> 9, j = idx & 511;
        wt[j * 32 + kk] = Wclf[idx];
    }
    int rl = tid >> 1, half = tid & 1;
    int kk = tid & 31, rg = tid >> 5;
    float acc[16] = {};
    for (int jc = 0; jc < 16; ++jc) {
        const float* src = (jc < 8 ? hsF : hsB) +
                           (size_t)(r0 + rl) * hstr + ((jc & 7) << 5) + (half << 4);
        float4 v0 = *(const float4*)(src + 0);
        float4 v1 = *(const float4*)(src + 4);
        float4 v2 = *(const float4*)(src + 8);
        float4 v3 = *(const float4*)(src + 12);
        __syncthreads();
        int jb = half << 4;
        xt[(jb+ 0)*128 + rl] = v0.x; xt[(jb+ 1)*128 + rl] = v0.y;
        xt[(jb+ 2)*128 + rl] = v0.z; xt[(jb+ 3)*128 + rl] = v0.w;
        xt[(jb+ 4)*128 + rl] = v1.x; xt[(jb+ 5)*128 + rl] = v1.y;
        xt[(jb+ 6)*128 + rl] = v1.z; xt[(jb+ 7)*128 + rl] = v1.w;
        xt[(jb+ 8)*128 + rl] = v2.x; xt[(jb+ 9)*128 + rl] = v2.y;
        xt[(jb+10)*128 + rl] = v2.z; xt[(jb+11)*128 + rl] = v2.w;
        xt[(jb+12)*128 + rl] = v3.x; xt[(jb+13)*128 + rl] = v3.y;
        xt[(jb+14)*128 + rl] = v3.z; xt[(jb+15)*128 + rl] = v3.w;
        __syncthreads();
        #pragma unroll
        for (int jp = 0; jp < 32; ++jp) {
            float w = wt[(jc * 32 + jp) * 32 + kk];
            const float* xr = &xt[jp * 128 + rg * 16];
            float4 x0 = *(const float4*)(xr + 0);
            float4 x1 = *(const float4*)(xr + 4);
            float4 x2 = *(const float4*)(xr + 8);
            float4 x3 = *(const float4*)(xr + 12);
            acc[ 0] += x0.x*w; acc[ 1] += x0.y*w; acc[ 2] += x0.z*w; acc[ 3] += x0.w*w;
            acc[ 4] += x1.x*w; acc[ 5] += x1.y*w; acc[ 6] += x1.z*w; acc[ 7] += x1.w*w;
            acc[ 8] += x2.x*w; acc[ 9] += x2.y*w; acc[10] += x2.z*w; acc[11] += x2.w*w;
            acc[12] += x3.x*w; acc[13] += x3.y*w; acc[14] += x3.z*w; acc[15] += x3.w*w;
        }
    }
    float bb = bclf[kk];
    #pragma unroll
    for (int i = 0; i < 16; ++i)
        logits[(size_t)(r0 + rg * 16 + i) * NK + kk] = acc[i] + bb;
}

// ---------------------------------------------------------------------------
// Viterbi: one wave per batch, ref-exact rounding order
// ---------------------------------------------------------------------------
__global__ __launch_bounds__(64)
void k_viterbi(const float* __restrict__ logits, const int* __restrict__ lengths,
               const float* __restrict__ st, const float* __restrict__ et,
               const float* __restrict__ trans, float* __restrict__ preds) {
    int b = blockIdx.x, lane = threadIdx.x;
    __shared__ unsigned char hist[NT - 1][NK];
    int len = lengths[b];
    int k = lane & 31;
    float wt[32];
    #pragma unroll
    for (int j = 0; j < 32; ++j) wt[j] = trans[j * NK + k];
    const float* lg = logits + (size_t)b * NT * NK;
    float score = st[k] + lg[k];
    for (int t = 1; t < NT; ++t) {
        float emis = lg[t * NK + k];
        float best = -3.4e38f; int bidx = 0;
        #pragma unroll
        for (int j = 0; j < 32; ++j) {
            float cand = (__shfl(score, j, 64) + wt[j]) + emis;
            if (cand > best) { best = cand; bidx = j; }
        }
        bool m = t < len;
        if (lane < 32) hist[t - 1][k] = (unsigned char)(m ? bidx : k);
        score = m ? best : score;
    }
    score += et[k];
    float bv = -3.4e38f; int btag = 0;
    #pragma unroll
    for (int j = 0; j < 32; ++j) {
        float v = __shfl(score, j, 64);
        if (v > bv) { bv = v; btag = j; }
    }
    __syncthreads();
    if (lane == 0) {
        int tag = btag;
        for (int t = NT - 1; t >= 1; --t) {
            preds[(size_t)b * NT + t] = (t < len) ? (float)tag : 0.f;
            tag = hist[t - 1][tag];
        }
        preds[(size_t)b * NT] = (float)tag;
    }
}

// ---------------------------------------------------------------------------
extern "C" void kernel_launch(void* const* d_in, const int* in_sizes, int n_in,
                              void* d_out, int out_size, void* d_ws, size_t ws_size,
                              hipStream_t stream) {
    (void)in_sizes; (void)n_in; (void)out_size;
    const float* x       = (const float*)d_in[0];
    const int*   lengths = (const int*)d_in[1];
    const float* Wih_f = (const float*)d_in[3];
    const float* Whh_f = (const float*)d_in[4];
    const float* b_f   = (const float*)d_in[5];
    const float* Wih_b = (const float*)d_in[6];
    const float* Whh_b = (const float*)d_in[7];
    const float* b_b   = (const float*)d_in[8];
    const float* W_clf = (const float*)d_in[9];
    const float* b_clf = (const float*)d_in[10];
    const float* st    = (const float*)d_in[11];
    const float* et    = (const float*)d_in[12];
    const float* trans = (const float*)d_in[13];

    float* logits = (float*)d_out;
    float* preds  = logits + (size_t)NBT * NK;

    // ww (2MB) + flags (0.5MB) live in the logits region of d_out — free
    // scratch until k_clf writes logits (after all lstm work is done).
    float* wwp = logits;                               // 524288 floats
    int*   flg = (int*)(logits + 524288);              // 131072 ints
    const size_t FLB = (size_t)131072 * 4;

    const size_t XPB = (size_t)NBT * NG * 4;          // 134,217,728
    const size_t HSB = (size_t)2 * NB * NT * NH * 4;  //  67,108,864 (serial only)
    bool conc = ws_size >= 2 * XPB;                   // 268.4 MB (hs aliased into xp)

    char* ws = (char*)d_ws;
    float* xp0 = (float*)ws;
    float* xp1 = conc ? (float*)(ws + XPB) : xp0;
    float *hsF, *hsB; int hstr;
    if (conc) {
        hsF = xp0; hsB = xp1; hstr = NG;              // alias gate-i columns
    } else {
        hsF = (float*)(ws + XPB); hsB = hsF + (size_t)NB * NT * NH; hstr = NH;
    }

    hipMemsetAsync(flg, 0, FLB, stream);
    k_wprep2<<<2048, 256, 0, stream>>>(Whh_f, Whh_b, wwp);

    if (conc) {
        k_gemm_f<<<dim3(16, 256), 256, 0, stream>>>(x, Wih_f, Wih_b, b_f, b_b,
                                                    xp0, xp1, 0);
        k_lstm2<<<256, 512, 0, stream>>>(xp0, xp1, wwp, lengths,
                                         hsF, hsB, hstr, flg, 0, 128);
    } else {
        k_gemm_f<<<dim3(8, 256), 256, 0, stream>>>(x, Wih_f, Wih_b, b_f, b_b,
                                                   xp0, xp0, 0);
        k_lstm2<<<128, 512, 0, stream>>>(xp0, xp0, wwp, lengths,
                                         hsF, hsB, hstr, flg, 0, 64);
        k_gemm_f<<<dim3(8, 256), 256, 0, stream>>>(x, Wih_f, Wih_b, b_f, b_b,
                                                   xp0, xp0, 8);
        k_lstm2<<<128, 512, 0, stream>>>(xp0, xp0, wwp, lengths,
                                         hsF, hsB, hstr, flg, 64, 64);
    }
    k_clf<<<256, 256, 0, stream>>>(hsF, hsB, hstr, W_clf, b_clf, logits);
    k_viterbi<<<NB, 64, 0, stream>>>(logits, lengths, st, et, trans, preds);
}

// Round 5
// 6742.742 us; speedup vs baseline: 2.1631x; 1.3807x over previous
//
#include <hip/hip_runtime.h>
#include <math.h>

#define NB 64
#define NT 512
#define ND 512
#define NH 256
#define NG 1024   // 4*H
#define NK 32
#define NBT (NB*NT)

__device__ __forceinline__ float sigf(float x) { return 1.f / (1.f + expf(-x)); }
__device__ __forceinline__ float hsum4(float4 v) { return v.x + v.y + v.z + v.w; }

// ---------------------------------------------------------------------------
// Weight prep for k_lstm3:
// ww[(((dir*4+s)*32 + g*8+j)*512 + tid)*4 + e] = Whh_dir[g*256+s*64+u][part*32+j*4+e]
//   where tid = part*64+u  (part=v-chunk 0..7, u=unit-in-slice 0..63)
// ---------------------------------------------------------------------------
__global__ void k_wprep3(const float* __restrict__ Wf, const float* __restrict__ Wb,
                         float* __restrict__ ww) {
    int f = blockIdx.x * 256 + threadIdx.x;      // 0 .. 524287
    int e   = f & 3;
    int tid = (f >> 2) & 511;
    int gj  = (f >> 11) & 31;
    int s   = (f >> 16) & 3;
    int dir = (f >> 18) & 1;
    int u = tid & 63, part = tid >> 6;
    int g = gj >> 3, j = gj & 7;
    const float* W = dir ? Wb : Wf;
    int row = g * 256 + s * 64 + u;
    int col = part * 32 + j * 4 + e;
    ww[f] = W[row * 256 + col];
}

// ---------------------------------------------------------------------------
// Fused input projection GEMM (both dirs): xp_dir = x @ Wih_dir^T + b_dir
// ---------------------------------------------------------------------------
__global__ __launch_bounds__(256, 4)
void k_gemm_f(const float* __restrict__ x, const float* __restrict__ Wf,
              const float* __restrict__ Wb, const float* __restrict__ bf,
              const float* __restrict__ bb, float* __restrict__ xpF,
              float* __restrict__ xpB, int bxBase) {
    __shared__ float As[16][132];
    __shared__ float Bs[16][132];
    int tid = threadIdx.x;
    int bx = blockIdx.x + bxBase;
    int dir = bx >> 3;
    const float* W    = dir ? Wb : Wf;
    const float* bias = dir ? bb : bf;
    float* xp         = dir ? xpB : xpF;
    int r0 = blockIdx.y << 7;
    int g0 = (bx & 7) << 7;
    int rl = tid >> 1, k8 = (tid & 1) << 3;
    const float* xa = x + (size_t)(r0 + rl) * ND + k8;
    const float* wa = W + (size_t)(g0 + rl) * ND + k8;
    int tx = tid & 15, ty = tid >> 4;
    float acc[8][8] = {};
    for (int kt = 0; kt < ND; kt += 16) {
        float4 a0 = *(const float4*)(xa + kt);
        float4 a1 = *(const float4*)(xa + kt + 4);
        float4 w0 = *(const float4*)(wa + kt);
        float4 w1 = *(const float4*)(wa + kt + 4);
        As[k8+0][rl]=a0.x; As[k8+1][rl]=a0.y; As[k8+2][rl]=a0.z; As[k8+3][rl]=a0.w;
        As[k8+4][rl]=a1.x; As[k8+5][rl]=a1.y; As[k8+6][rl]=a1.z; As[k8+7][rl]=a1.w;
        Bs[k8+0][rl]=w0.x; Bs[k8+1][rl]=w0.y; Bs[k8+2][rl]=w0.z; Bs[k8+3][rl]=w0.w;
        Bs[k8+4][rl]=w1.x; Bs[k8+5][rl]=w1.y; Bs[k8+6][rl]=w1.z; Bs[k8+7][rl]=w1.w;
        __syncthreads();
        #pragma unroll
        for (int kk = 0; kk < 16; ++kk) {
            float4 av0 = *(const float4*)(&As[kk][ty << 3]);
            float4 av1 = *(const float4*)(&As[kk][(ty << 3) + 4]);
            float4 bv0 = *(const float4*)(&Bs[kk][tx << 3]);
            float4 bv1 = *(const float4*)(&Bs[kk][(tx << 3) + 4]);
            float aa[8] = {av0.x, av0.y, av0.z, av0.w, av1.x, av1.y, av1.z, av1.w};
            float bbv[8] = {bv0.x, bv0.y, bv0.z, bv0.w, bv1.x, bv1.y, bv1.z, bv1.w};
            #pragma unroll
            for (int i = 0; i < 8; ++i)
                #pragma unroll
                for (int j = 0; j < 8; ++j)
                    acc[i][j] += aa[i] * bbv[j];
        }
        __syncthreads();
    }
    float bv[8];
    #pragma unroll
    for (int j = 0; j < 8; ++j) bv[j] = bias[g0 + (tx << 3) + j];
    #pragma unroll
    for (int i = 0; i < 8; ++i) {
        float* orow = xp + (size_t)(r0 + (ty << 3) + i) * NG + g0 + (tx << 3);
        float4 o0 = {acc[i][0]+bv[0], acc[i][1]+bv[1], acc[i][2]+bv[2], acc[i][3]+bv[3]};
        float4 o1 = {acc[i][4]+bv[4], acc[i][5]+bv[5], acc[i][6]+bv[6], acc[i][7]+bv[7]};
        *(float4*)orow = o0;
        *(float4*)(orow + 4) = o1;
    }
}

// ---------------------------------------------------------------------------
// LSTM recurrence, 4 blocks per chain (u-slices of 64), one direction per
// pass. 512 threads: thread (part=tid>>6 in 0..7 = 32-wide v-chunk,
// u=tid&63). Weights/thread: 32 float4 = 16 named VGPR quads (gates i,f) +
// 16 LDS quads (gates g,o). Honest VGPR need ~110 -> fits the 128 budget.
// Sibling blocks of a chain are XCD-swizzled; h exchanged via hs rows in L2
// with per-step release/acquire flags; own slice via LDS.
// ---------------------------------------------------------------------------
#define FMA4(A, W, H) { (A).x += (W).x*(H).x; (A).y += (W).y*(H).y; \
                        (A).z += (W).z*(H).z; (A).w += (W).w*(H).w; }

#define DOTJ(j, H4) { float4 h_ = (H4); \
    FMA4(accA, wA##j, h_) FMA4(accB, wB##j, h_) \
    { float4 l_ = lds_w[(j)*512 + tid];     FMA4(accC, l_, h_) } \
    { float4 l_ = lds_w[(8+(j))*512 + tid]; FMA4(accD, l_, h_) } }

#define DOT8(H) DOTJ(0,H(0)) DOTJ(1,H(1)) DOTJ(2,H(2)) DOTJ(3,H(3)) \
                DOTJ(4,H(4)) DOTJ(5,H(5)) DOTJ(6,H(6)) DOTJ(7,H(7))

__global__ void
__attribute__((amdgpu_flat_work_group_size(512, 512)))
k_lstm3(const float* __restrict__ xp, const float* __restrict__ ww,
        const int* __restrict__ lengths, float* hsD, int hstr,
        int* flags, int dir) {
    int bi = blockIdx.x;
    int k5 = bi >> 3;
    int c  = (bi & 7) + ((k5 >> 2) << 3);   // chain/batch 0..63, siblings same XCD
    int s  = k5 & 3;                        // u-slice 0..3
    int tid = threadIdx.x;
    int u = tid & 63;
    int part = tid >> 6;                    // v-chunk 0..7
    int slice = part >> 1;                  // which u-slice owns this v-chunk
    int len = lengths[c];

    __shared__ float4 lds_w[16 * 512];      // 128 KB: gates g,o weights
    __shared__ __align__(16) float lds_h[2][64];
    __shared__ float4 lds_part[8 * 64];     // 8 KB

    const float4* wwp = (const float4*)ww;
    int qb = ((dir * 4 + s) * 32) * 512 + tid;
    float4 wA0 = wwp[qb +  0*512], wA1 = wwp[qb +  1*512];
    float4 wA2 = wwp[qb +  2*512], wA3 = wwp[qb +  3*512];
    float4 wA4 = wwp[qb +  4*512], wA5 = wwp[qb +  5*512];
    float4 wA6 = wwp[qb +  6*512], wA7 = wwp[qb +  7*512];
    float4 wB0 = wwp[qb +  8*512], wB1 = wwp[qb +  9*512];
    float4 wB2 = wwp[qb + 10*512], wB3 = wwp[qb + 11*512];
    float4 wB4 = wwp[qb + 12*512], wB5 = wwp[qb + 13*512];
    float4 wB6 = wwp[qb + 14*512], wB7 = wwp[qb + 15*512];
    #pragma unroll
    for (int j = 0; j < 16; ++j)
        lds_w[j * 512 + tid] = wwp[qb + (16 + j) * 512];

    if (tid < 64) { lds_h[0][tid] = 0.f; lds_h[1][tid] = 0.f; }
    float c_state = 0.f;
    __syncthreads();

    float* hbase = hsD + (size_t)c * NT * hstr;
    int* flBase = flags + (c << 11);        // c*4*512
    int flSelf = (s << 9);

    int cur = 0;
    for (int tt = 0; tt < NT; ++tt) {
        int t = dir ? (NT - 1 - tt) : tt;
        bool active = t < len;

        float x0 = 0.f, x1 = 0.f, x2 = 0.f, x3 = 0.f;
        if (tid < 64) {      // issue xp loads early (gate cols g*256 + s*64+u)
            const float* xr = xp + ((size_t)c * NT + t) * NG + s * 64 + u;
            x0 = xr[0]; x1 = xr[256]; x2 = xr[512]; x3 = xr[768];
        }
        // pollers: wave 0 lanes 0..3 (skip own slice) acquire partner flags
        if (tt > 0 && active && tid < 4 && tid != s) {
            const int* fp = flBase + (tid << 9) + (tt - 1);
            while (__hip_atomic_load(fp, __ATOMIC_ACQUIRE,
                                     __HIP_MEMORY_SCOPE_AGENT) == 0) {}
        }
        __syncthreads();     // partner flags seen; lds_h[cur] from last step visible

        float4 accA = {0.f,0.f,0.f,0.f}, accB = accA, accC = accA, accD = accA;
        if (tt > 0 && active) {
            if (slice == s) {
                const float* hb = &lds_h[cur][(part & 1) * 32];
                #define HL(j) (*(const float4*)(hb + (j) * 4))
                DOT8(HL)
                #undef HL
            } else {
                int t_prev = dir ? (t + 1) : (t - 1);
                const float4* hg = (const float4*)(hbase + (size_t)t_prev * hstr
                                                   + (part << 5));
                #define HG(j) (hg[(j)])
                DOT8(HG)
                #undef HG
            }
        }
        lds_part[(part << 6) + u] = make_float4(hsum4(accA), hsum4(accB),
                                                hsum4(accC), hsum4(accD));
        __syncthreads();

        if (tid < 64) {      // wave 0: reduce + gate update + publish h
            float4 q0 = lds_part[u],        q1 = lds_part[64 + u];
            float4 q2 = lds_part[128 + u],  q3 = lds_part[192 + u];
            float4 q4 = lds_part[256 + u],  q5 = lds_part[320 + u];
            float4 q6 = lds_part[384 + u],  q7 = lds_part[448 + u];
            float pi = q0.x+q1.x+q2.x+q3.x+q4.x+q5.x+q6.x+q7.x + x0;
            float pf = q0.y+q1.y+q2.y+q3.y+q4.y+q5.y+q6.y+q7.y + x1;
            float pg = q0.z+q1.z+q2.z+q3.z+q4.z+q5.z+q6.z+q7.z + x2;
            float po = q0.w+q1.w+q2.w+q3.w+q4.w+q5.w+q6.w+q7.w + x3;
            float h_old = lds_h[cur][u];
            float hv;
            if (active) {
                float gi = sigf(pi), gf = sigf(pf), gg = tanhf(pg), go = sigf(po);
                c_state = gf * c_state + gi * gg;
                hv = go * tanhf(c_state);
            } else {
                hv = h_old;
            }
            lds_h[cur ^ 1][u] = hv;
            hbase[(size_t)t * hstr + s * 64 + u] = hv;
        }
        // release: wave 0 program order after its global h stores; release
        // semantics drain vmcnt. No barrier needed before next iteration's
        // poll/barrier (LDS reuse ordered by next step's first barrier).
        if (tid == 0)
            __hip_atomic_store(flBase + flSelf + tt, 1, __ATOMIC_RELEASE,
                               __HIP_MEMORY_SCOPE_AGENT);
        cur ^= 1;
    }
}

// ---------------------------------------------------------------------------
// Classifier GEMM: logits[r][kk] = sum_j concat(hsF,hsB)[r][j]*W_clf[kk][j]+b
// ---------------------------------------------------------------------------
__global__ __launch_bounds__(256, 4)
void k_clf(const float* __restrict__ hsF, const float* __restrict__ hsB,
           int hstr, const float* __restrict__ Wclf, const float* __restrict__ bclf,
           float* __restrict__ logits) {
    __shared__ float wt[512 * 32];   // 64 KB  [j][kk]
    __shared__ float xt[32 * 128];   // 16 KB  [j'][r]
    int tid = threadIdx.x;
    int r0 = blockIdx.x << 7;
    #pragma unroll
    for (int e = 0; e < 64; ++e) {
        int idx = e * 256 + tid;           // flat over [32][512]
        int kk = idx >> 9, j = idx & 511;
        wt[j * 32 + kk] = Wclf[idx];
    }
    int rl = tid >> 1, half = tid & 1;
    int kk = tid & 31, rg = tid >> 5;
    float acc[16] = {};
    for (int jc = 0; jc < 16; ++jc) {
        const float* src = (jc < 8 ? hsF : hsB) +
                           (size_t)(r0 + rl) * hstr + ((jc & 7) << 5) + (half << 4);
        float4 v0 = *(const float4*)(src + 0);
        float4 v1 = *(const float4*)(src + 4);
        float4 v2 = *(const float4*)(src + 8);
        float4 v3 = *(const float4*)(src + 12);
        __syncthreads();
        int jb = half << 4;
        xt[(jb+ 0)*128 + rl] = v0.x; xt[(jb+ 1)*128 + rl] = v0.y;
        xt[(jb+ 2)*128 + rl] = v0.z; xt[(jb+ 3)*128 + rl] = v0.w;
        xt[(jb+ 4)*128 + rl] = v1.x; xt[(jb+ 5)*128 + rl] = v1.y;
        xt[(jb+ 6)*128 + rl] = v1.z; xt[(jb+ 7)*128 + rl] = v1.w;
        xt[(jb+ 8)*128 + rl] = v2.x; xt[(jb+ 9)*128 + rl] = v2.y;
        xt[(jb+10)*128 + rl] = v2.z; xt[(jb+11)*128 + rl] = v2.w;
        xt[(jb+12)*128 + rl] = v3.x; xt[(jb+13)*128 + rl] = v3.y;
        xt[(jb+14)*128 + rl] = v3.z; xt[(jb+15)*128 + rl] = v3.w;
        __syncthreads();
        #pragma unroll
        for (int jp = 0; jp < 32; ++jp) {
            float w = wt[(jc * 32 + jp) * 32 + kk];
            const float* xr = &xt[jp * 128 + rg * 16];
            float4 x0 = *(const float4*)(xr + 0);
            float4 x1 = *(const float4*)(xr + 4);
            float4 x2 = *(const float4*)(xr + 8);
            float4 x3 = *(const float4*)(xr + 12);
            acc[ 0] += x0.x*w; acc[ 1] += x0.y*w; acc[ 2] += x0.z*w; acc[ 3] += x0.w*w;
            acc[ 4] += x1.x*w; acc[ 5] += x1.y*w; acc[ 6] += x1.z*w; acc[ 7] += x1.w*w;
            acc[ 8] += x2.x*w; acc[ 9] += x2.y*w; acc[10] += x2.z*w; acc[11] += x2.w*w;
            acc[12] += x3.x*w; acc[13] += x3.y*w; acc[14] += x3.z*w; acc[15] += x3.w*w;
        }
    }
    float bb = bclf[kk];
    #pragma unroll
    for (int i = 0; i < 16; ++i)
        logits[(size_t)(r0 + rg * 16 + i) * NK + kk] = acc[i] + bb;
}

// ---------------------------------------------------------------------------
// Viterbi: one wave per batch, ref-exact rounding order
// ---------------------------------------------------------------------------
__global__ __launch_bounds__(64)
void k_viterbi(const float* __restrict__ logits, const int* __restrict__ lengths,
               const float* __restrict__ st, const float* __restrict__ et,
               const float* __restrict__ trans, float* __restrict__ preds) {
    int b = blockIdx.x, lane = threadIdx.x;
    __shared__ unsigned char hist[NT - 1][NK];
    int len = lengths[b];
    int k = lane & 31;
    float wt[32];
    #pragma unroll
    for (int j = 0; j < 32; ++j) wt[j] = trans[j * NK + k];
    const float* lg = logits + (size_t)b * NT * NK;
    float score = st[k] + lg[k];
    for (int t = 1; t < NT; ++t) {
        float emis = lg[t * NK + k];
        float best = -3.4e38f; int bidx = 0;
        #pragma unroll
        for (int j = 0; j < 32; ++j) {
            float cand = (__shfl(score, j, 64) + wt[j]) + emis;
            if (cand > best) { best = cand; bidx = j; }
        }
        bool m = t < len;
        if (lane < 32) hist[t - 1][k] = (unsigned char)(m ? bidx : k);
        score = m ? best : score;
    }
    score += et[k];
    float bv = -3.4e38f; int btag = 0;
    #pragma unroll
    for (int j = 0; j < 32; ++j) {
        float v = __shfl(score, j, 64);
        if (v > bv) { bv = v; btag = j; }
    }
    __syncthreads();
    if (lane == 0) {
        int tag = btag;
        for (int t = NT - 1; t >= 1; --t) {
            preds[(size_t)b * NT + t] = (t < len) ? (float)tag : 0.f;
            tag = hist[t - 1][tag];
        }
        preds[(size_t)b * NT] = (float)tag;
    }
}

// ---------------------------------------------------------------------------
extern "C" void kernel_launch(void* const* d_in, const int* in_sizes, int n_in,
                              void* d_out, int out_size, void* d_ws, size_t ws_size,
                              hipStream_t stream) {
    (void)in_sizes; (void)n_in; (void)out_size;
    const float* x       = (const float*)d_in[0];
    const int*   lengths = (const int*)d_in[1];
    const float* Wih_f = (const float*)d_in[3];
    const float* Whh_f = (const float*)d_in[4];
    const float* b_f   = (const float*)d_in[5];
    const float* Wih_b = (const float*)d_in[6];
    const float* Whh_b = (const float*)d_in[7];
    const float* b_b   = (const float*)d_in[8];
    const float* W_clf = (const float*)d_in[9];
    const float* b_clf = (const float*)d_in[10];
    const float* st    = (const float*)d_in[11];
    const float* et    = (const float*)d_in[12];
    const float* trans = (const float*)d_in[13];

    float* logits = (float*)d_out;
    float* preds  = logits + (size_t)NBT * NK;

    // scratch inside the (not-yet-written) logits region of d_out:
    // ww = 524288 floats (2MB), flags = 262144 ints (1MB); logits is 4MB.
    float* wwp = logits;
    int*   flg = (int*)(logits + 524288);
    const size_t FLB = (size_t)262144 * 4;

    const size_t XPB = (size_t)NBT * NG * 4;          // 134,217,728
    bool conc = ws_size >= 2 * XPB;

    char* ws = (char*)d_ws;
    float* xp0 = (float*)ws;
    float* xp1 = conc ? (float*)(ws + XPB) : xp0;
    float *hsF, *hsB; int hstr;
    if (conc) {
        hsF = xp0; hsB = xp1; hstr = NG;              // h aliases gate-i columns
    } else {
        hsF = (float*)(ws + XPB); hsB = hsF + (size_t)NB * NT * NH; hstr = NH;
    }

    hipMemsetAsync(flg, 0, FLB, stream);
    k_wprep3<<<2048, 256, 0, stream>>>(Whh_f, Whh_b, wwp);

    if (conc) {
        k_gemm_f<<<dim3(16, 256), 256, 0, stream>>>(x, Wih_f, Wih_b, b_f, b_b,
                                                    xp0, xp1, 0);
        k_lstm3<<<256, 512, 0, stream>>>(xp0, wwp, lengths, hsF, hstr, flg, 0);
        k_lstm3<<<256, 512, 0, stream>>>(xp1, wwp, lengths, hsB, hstr,
                                         flg + 131072, 1);
    } else {
        k_gemm_f<<<dim3(8, 256), 256, 0, stream>>>(x, Wih_f, Wih_b, b_f, b_b,
                                                   xp0, xp0, 0);
        k_lstm3<<<256, 512, 0, stream>>>(xp0, wwp, lengths, hsF, hstr, flg, 0);
        k_gemm_f<<<dim3(8, 256), 256, 0, stream>>>(x, Wih_f, Wih_b, b_f, b_b,
                                                   xp0, xp0, 8);
        k_lstm3<<<256, 512, 0, stream>>>(xp0, wwp, lengths, hsB, hstr,
                                         flg + 131072, 1);
    }
    k_clf<<<256, 256, 0, stream>>>(hsF, hsB, hstr, W_clf, b_clf, logits);
    k_viterbi<<<NB, 64, 0, stream>>>(logits, lengths, st, et, trans, preds);
}

// Round 6
// 5772.713 us; speedup vs baseline: 2.5266x; 1.1680x over previous
//
#include <hip/hip_runtime.h>
#include <math.h>

#define NB 64
#define NT 512
#define ND 512
#define NH 256
#define NG 1024   // 4*H
#define NK 32
#define NBT (NB*NT)
#define NBAT 4    // batches per lstm block

__device__ __forceinline__ float sigf(float x) { return 1.f / (1.f + expf(-x)); }
__device__ __forceinline__ float hsum4(float4 v) { return v.x + v.y + v.z + v.w; }

// ---------------------------------------------------------------------------
// Weight prep (unchanged layout from round 5):
// ww[(((dir*4+s)*32 + g*8+j)*512 + tid)*4 + e] = Whh_dir[g*256+s*64+u][part*32+j*4+e]
//   where tid = part*64+u
// ---------------------------------------------------------------------------
__global__ void k_wprep3(const float* __restrict__ Wf, const float* __restrict__ Wb,
                         float* __restrict__ ww) {
    int f = blockIdx.x * 256 + threadIdx.x;      // 0 .. 524287
    int e   = f & 3;
    int tid = (f >> 2) & 511;
    int gj  = (f >> 11) & 31;
    int s   = (f >> 16) & 3;
    int dir = (f >> 18) & 1;
    int u = tid & 63, part = tid >> 6;
    int g = gj >> 3, j = gj & 7;
    const float* W = dir ? Wb : Wf;
    int row = g * 256 + s * 64 + u;
    int col = part * 32 + j * 4 + e;
    ww[f] = W[row * 256 + col];
}

// ---------------------------------------------------------------------------
// Fused input projection GEMM (both dirs): xp_dir = x @ Wih_dir^T + b_dir
// ---------------------------------------------------------------------------
__global__ __launch_bounds__(256, 4)
void k_gemm_f(const float* __restrict__ x, const float* __restrict__ Wf,
              const float* __restrict__ Wb, const float* __restrict__ bf,
              const float* __restrict__ bb, float* __restrict__ xpF,
              float* __restrict__ xpB, int bxBase) {
    __shared__ float As[16][132];
    __shared__ float Bs[16][132];
    int tid = threadIdx.x;
    int bx = blockIdx.x + bxBase;
    int dir = bx >> 3;
    const float* W    = dir ? Wb : Wf;
    const float* bias = dir ? bb : bf;
    float* xp         = dir ? xpB : xpF;
    int r0 = blockIdx.y << 7;
    int g0 = (bx & 7) << 7;
    int rl = tid >> 1, k8 = (tid & 1) << 3;
    const float* xa = x + (size_t)(r0 + rl) * ND + k8;
    const float* wa = W + (size_t)(g0 + rl) * ND + k8;
    int tx = tid & 15, ty = tid >> 4;
    float acc[8][8] = {};
    for (int kt = 0; kt < ND; kt += 16) {
        float4 a0 = *(const float4*)(xa + kt);
        float4 a1 = *(const float4*)(xa + kt + 4);
        float4 w0 = *(const float4*)(wa + kt);
        float4 w1 = *(const float4*)(wa + kt + 4);
        As[k8+0][rl]=a0.x; As[k8+1][rl]=a0.y; As[k8+2][rl]=a0.z; As[k8+3][rl]=a0.w;
        As[k8+4][rl]=a1.x; As[k8+5][rl]=a1.y; As[k8+6][rl]=a1.z; As[k8+7][rl]=a1.w;
        Bs[k8+0][rl]=w0.x; Bs[k8+1][rl]=w0.y; Bs[k8+2][rl]=w0.z; Bs[k8+3][rl]=w0.w;
        Bs[k8+4][rl]=w1.x; Bs[k8+5][rl]=w1.y; Bs[k8+6][rl]=w1.z; Bs[k8+7][rl]=w1.w;
        __syncthreads();
        #pragma unroll
        for (int kk = 0; kk < 16; ++kk) {
            float4 av0 = *(const float4*)(&As[kk][ty << 3]);
            float4 av1 = *(const float4*)(&As[kk][(ty << 3) + 4]);
            float4 bv0 = *(const float4*)(&Bs[kk][tx << 3]);
            float4 bv1 = *(const float4*)(&Bs[kk][(tx << 3) + 4]);
            float aa[8] = {av0.x, av0.y, av0.z, av0.w, av1.x, av1.y, av1.z, av1.w};
            float bbv[8] = {bv0.x, bv0.y, bv0.z, bv0.w, bv1.x, bv1.y, bv1.z, bv1.w};
            #pragma unroll
            for (int i = 0; i < 8; ++i)
                #pragma unroll
                for (int j = 0; j < 8; ++j)
                    acc[i][j] += aa[i] * bbv[j];
        }
        __syncthreads();
    }
    float bv[8];
    #pragma unroll
    for (int j = 0; j < 8; ++j) bv[j] = bias[g0 + (tx << 3) + j];
    #pragma unroll
    for (int i = 0; i < 8; ++i) {
        float* orow = xp + (size_t)(r0 + (ty << 3) + i) * NG + g0 + (tx << 3);
        float4 o0 = {acc[i][0]+bv[0], acc[i][1]+bv[1], acc[i][2]+bv[2], acc[i][3]+bv[3]};
        float4 o1 = {acc[i][4]+bv[4], acc[i][5]+bv[5], acc[i][6]+bv[6], acc[i][7]+bv[7]};
        *(float4*)orow = o0;
        *(float4*)(orow + 4) = o1;
    }
}

// ---------------------------------------------------------------------------
// LSTM recurrence, 4 blocks per chain-set (u-slices of 64), NBAT=4 batches
// per block, both dirs in one dispatch. 512 threads: wave wv=tid>>6 = v-chunk
// (part) for dots; waves 0..3 also own batch wv for gate updates.
// Weights/thread: 32 quads = 20 named VGPR + 12 LDS. Partner h staged into
// LDS hfull[4][256] once per step; latency paid once, amortized over 4 dots.
// ---------------------------------------------------------------------------
#define FMA4(A, W, H) { (A).x += (W).x*(H).x; (A).y += (W).y*(H).y; \
                        (A).z += (W).z*(H).z; (A).w += (W).w*(H).w; }

#define DECLR(g) \
    float4 wr##g##_0 = wwp[qb + ((g)*8+0)*512]; \
    float4 wr##g##_1 = wwp[qb + ((g)*8+1)*512]; \
    float4 wr##g##_2 = wwp[qb + ((g)*8+2)*512]; \
    float4 wr##g##_3 = wwp[qb + ((g)*8+3)*512]; \
    float4 wr##g##_4 = wwp[qb + ((g)*8+4)*512];

#define DOTRJ(j) { float4 h_ = *(const float4*)(hb + (j)*4); \
    FMA4(a0, wr0_##j, h_) FMA4(a1, wr1_##j, h_) \
    FMA4(a2, wr2_##j, h_) FMA4(a3, wr3_##j, h_) }

#define DOTLJ(jj, j) { float4 h_ = *(const float4*)(hb + (j)*4); \
    { float4 l_ = lds_w[(0*3+(jj))*512 + tid]; FMA4(a0, l_, h_) } \
    { float4 l_ = lds_w[(1*3+(jj))*512 + tid]; FMA4(a1, l_, h_) } \
    { float4 l_ = lds_w[(2*3+(jj))*512 + tid]; FMA4(a2, l_, h_) } \
    { float4 l_ = lds_w[(3*3+(jj))*512 + tid]; FMA4(a3, l_, h_) } }

#define DOTALL DOTRJ(0) DOTRJ(1) DOTRJ(2) DOTRJ(3) DOTRJ(4) \
               DOTLJ(0,5) DOTLJ(1,6) DOTLJ(2,7)

__global__ void
__attribute__((amdgpu_flat_work_group_size(512, 512)))
k_lstm4(const float* __restrict__ xpF, const float* __restrict__ xpB,
        const float* __restrict__ ww, const int* __restrict__ lengths,
        float* hsF, float* hsB, int hstr, int* flags, int gBase) {
    int bi = blockIdx.x;
    int g   = (bi & 7) + 8 * (bi >> 5) + gBase;  // 0..31: dir*16 + group
    int s   = (bi >> 3) & 3;                     // u-slice; siblings share bi&7 -> same XCD
    int dir = g >> 4;
    int b0  = (g & 15) * NBAT;
    const float* xp = dir ? xpB : xpF;
    float* hsD      = dir ? hsB : hsF;

    int tid = threadIdx.x;
    int u  = tid & 63;
    int wv = tid >> 6;                           // wave = v-chunk (part) 0..7

    __shared__ float4 lds_w[12 * 512];           // 96 KB: w quads j=5..7 per gate
    __shared__ __align__(16) float hfull[NBAT][256];
    __shared__ float4 lds_part[NBAT][8][64];     // 32 KB
    __shared__ int len4[NBAT];

    const float4* wwp = (const float4*)ww;
    int qb = ((dir * 4 + s) * 32) * 512 + tid;

    DECLR(0) DECLR(1) DECLR(2) DECLR(3)          // 20 named quads -> VGPRs
    #pragma unroll
    for (int gg = 0; gg < 4; ++gg)
        #pragma unroll
        for (int jj = 0; jj < 3; ++jj)
            lds_w[(gg * 3 + jj) * 512 + tid] = wwp[qb + (gg * 8 + 5 + jj) * 512];

    if (tid < NBAT) len4[tid] = lengths[b0 + tid];
    ((float*)hfull)[tid] = 0.f;
    ((float*)hfull)[tid + 512] = 0.f;
    float c_state = 0.f;
    __syncthreads();

    // precomputed staging assignment (threads 0..191): 48 quads per batch
    int stb  = (tid < 192) ? (tid / 48) : 0;
    int stq  = (tid < 192) ? (tid - stb * 48) : 0;
    int stpsi = stq >> 4, stq16 = stq & 15;
    int stsl = stpsi + (stpsi >= s);             // partner slice
    float* stdst = &hfull[stb][stsl * 64 + stq16 * 4];
    const float* stsrc0 = hsD + (size_t)(b0 + stb) * NT * hstr + stsl * 64 + stq16 * 4;

    // poller assignment (threads 0..15)
    int pb = tid & 3, ps = tid >> 2;
    const int* pollp = flags + ((((dir << 6) + b0 + pb) << 2) + ps) * 512;

    // update-wave globals
    float* hwp = hsD + (size_t)(b0 + wv) * NT * hstr + (s << 6) + u;   // wv<4 only
    int* flrel = flags + ((((dir << 6) + b0 + wv) << 2) + s) * 512;

    for (int tt = 0; tt < NT; ++tt) {
        int t = dir ? (NT - 1 - tt) : tt;

        // A: xp prefetch (wave b loads batch b's 4 gate columns)
        float x0 = 0.f, x1 = 0.f, x2 = 0.f, x3 = 0.f;
        if (wv < NBAT) {
            const float* xr = xp + ((size_t)(b0 + wv) * NT + t) * NG + (s << 6) + u;
            x0 = xr[0]; x1 = xr[256]; x2 = xr[512]; x3 = xr[768];
        }
        // B: poll 12 partner flags (lanes 0..15, skip own slice / inactive)
        if (tt > 0 && tid < 16 && ps != s && t < len4[pb]) {
            const int* fp = pollp + (tt - 1);
            while (__hip_atomic_load(fp, __ATOMIC_ACQUIRE,
                                     __HIP_MEMORY_SCOPE_AGENT) == 0) {}
        }
        __syncthreads();   // C: flags acquired; prev-step hfull own-writes visible

        // D: stage partner h into hfull (192 threads, one quad each)
        if (tt > 0 && tid < 192 && t < len4[stb]) {
            int t_prev = dir ? (t + 1) : (t - 1);
            *(float4*)stdst = *(const float4*)(stsrc0 + (size_t)t_prev * hstr);
        }
        __syncthreads();   // E

        // F: 4 dots (block-uniform skip per batch)
        #pragma unroll
        for (int b = 0; b < NBAT; ++b) {
            if (tt > 0 && t < len4[b]) {
                const float* hb = &hfull[b][wv << 5];
                float4 a0 = {0.f,0.f,0.f,0.f}, a1 = a0, a2 = a0, a3 = a0;
                DOTALL
                lds_part[b][wv][u] = make_float4(hsum4(a0), hsum4(a1),
                                                 hsum4(a2), hsum4(a3));
            }
        }
        __syncthreads();   // G

        // H: update (wave b owns batch b)
        if (wv < NBAT) {
            bool act = t < len4[wv];
            float pi, pf, pg, po;
            if (tt > 0 && act) {
                float4 q0 = lds_part[wv][0][u], q1 = lds_part[wv][1][u];
                float4 q2 = lds_part[wv][2][u], q3 = lds_part[wv][3][u];
                float4 q4 = lds_part[wv][4][u], q5 = lds_part[wv][5][u];
                float4 q6 = lds_part[wv][6][u], q7 = lds_part[wv][7][u];
                pi = q0.x+q1.x+q2.x+q3.x+q4.x+q5.x+q6.x+q7.x + x0;
                pf = q0.y+q1.y+q2.y+q3.y+q4.y+q5.y+q6.y+q7.y + x1;
                pg = q0.z+q1.z+q2.z+q3.z+q4.z+q5.z+q6.z+q7.z + x2;
                po = q0.w+q1.w+q2.w+q3.w+q4.w+q5.w+q6.w+q7.w + x3;
            } else {
                pi = x0; pf = x1; pg = x2; po = x3;
            }
            float h_old = hfull[wv][(s << 6) + u];
            float hv = h_old;
            if (act) {
                float gi = sigf(pi), gf = sigf(pf), gg = tanhf(pg), go = sigf(po);
                c_state = gf * c_state + gi * gg;
                hv = go * tanhf(c_state);
            }
            hfull[wv][(s << 6) + u] = hv;
            hwp[(size_t)t * hstr] = hv;          // publish to partners (L2)
        }
        // I: release (lane 0 of wave b; release drains the wave's stores)
        if (wv < NBAT && u == 0)
            __hip_atomic_store(flrel + tt, 1, __ATOMIC_RELEASE,
                               __HIP_MEMORY_SCOPE_AGENT);
    }
}

// ---------------------------------------------------------------------------
// Classifier GEMM: logits[r][kk] = sum_j concat(hsF,hsB)[r][j]*W_clf[kk][j]+b
// ---------------------------------------------------------------------------
__global__ __launch_bounds__(256, 4)
void k_clf(const float* __restrict__ hsF, const float* __restrict__ hsB,
           int hstr, const float* __restrict__ Wclf, const float* __restrict__ bclf,
           float* __restrict__ logits) {
    __shared__ float wt[512 * 32];   // 64 KB  [j][kk]
    __shared__ float xt[32 * 128];   // 16 KB  [j'][r]
    int tid = threadIdx.x;
    int r0 = blockIdx.x << 7;
    #pragma unroll
    for (int e = 0; e < 64; ++e) {
        int idx = e * 256 + tid;           // flat over [32][512]
        int kk = idx >> 9, j = idx & 511;
        wt[j * 32 + kk] = Wclf[idx];
    }
    int rl = tid >> 1, half = tid & 1;
    int kk = tid & 31, rg = tid >> 5;
    float acc[16] = {};
    for (int jc = 0; jc < 16; ++jc) {
        const float* src = (jc < 8 ? hsF : hsB) +
                           (size_t)(r0 + rl) * hstr + ((jc & 7) << 5) + (half << 4);
        float4 v0 = *(const float4*)(src + 0);
        float4 v1 = *(const float4*)(src + 4);
        float4 v2 = *(const float4*)(src + 8);
        float4 v3 = *(const float4*)(src + 12);
        __syncthreads();
        int jb = half << 4;
        xt[(jb+ 0)*128 + rl] = v0.x; xt[(jb+ 1)*128 + rl] = v0.y;
        xt[(jb+ 2)*128 + rl] = v0.z; xt[(jb+ 3)*128 + rl] = v0.w;
        xt[(jb+ 4)*128 + rl] = v1.x; xt[(jb+ 5)*128 + rl] = v1.y;
        xt[(jb+ 6)*128 + rl] = v1.z; xt[(jb+ 7)*128 + rl] = v1.w;
        xt[(jb+ 8)*128 + rl] = v2.x; xt[(jb+ 9)*128 + rl] = v2.y;
        xt[(jb+10)*128 + rl] = v2.z; xt[(jb+11)*128 + rl] = v2.w;
        xt[(jb+12)*128 + rl] = v3.x; xt[(jb+13)*128 + rl] = v3.y;
        xt[(jb+14)*128 + rl] = v3.z; xt[(jb+15)*128 + rl] = v3.w;
        __syncthreads();
        #pragma unroll
        for (int jp = 0; jp < 32; ++jp) {
            float w = wt[(jc * 32 + jp) * 32 + kk];
            const float* xr = &xt[jp * 128 + rg * 16];
            float4 x0 = *(const float4*)(xr + 0);
            float4 x1 = *(const float4*)(xr + 4);
            float4 x2 = *(const float4*)(xr + 8);
            float4 x3 = *(const float4*)(xr + 12);
            acc[ 0] += x0.x*w; acc[ 1] += x0.y*w; acc[ 2] += x0.z*w; acc[ 3] += x0.w*w;
            acc[ 4] += x1.x*w; acc[ 5] += x1.y*w; acc[ 6] += x1.z*w; acc[ 7] += x1.w*w;
            acc[ 8] += x2.x*w; acc[ 9] += x2.y*w; acc[10] += x2.z*w; acc[11] += x2.w*w;
            acc[12] += x3.x*w; acc[13] += x3.y*w; acc[14] += x3.z*w; acc[15] += x3.w*w;
        }
    }
    float bb = bclf[kk];
    #pragma unroll
    for (int i = 0; i < 16; ++i)
        logits[(size_t)(r0 + rg * 16 + i) * NK + kk] = acc[i] + bb;
}

// ---------------------------------------------------------------------------
// Viterbi: one wave per batch, ref-exact rounding order
// ---------------------------------------------------------------------------
__global__ __launch_bounds__(64)
void k_viterbi(const float* __restrict__ logits, const int* __restrict__ lengths,
               const float* __restrict__ st, const float* __restrict__ et,
               const float* __restrict__ trans, float* __restrict__ preds) {
    int b = blockIdx.x, lane = threadIdx.x;
    __shared__ unsigned char hist[NT - 1][NK];
    int len = lengths[b];
    int k = lane & 31;
    float wt[32];
    #pragma unroll
    for (int j = 0; j < 32; ++j) wt[j] = trans[j * NK + k];
    const float* lg = logits + (size_t)b * NT * NK;
    float score = st[k] + lg[k];
    for (int t = 1; t < NT; ++t) {
        float emis = lg[t * NK + k];
        float best = -3.4e38f; int bidx = 0;
        #pragma unroll
        for (int j = 0; j < 32; ++j) {
            float cand = (__shfl(score, j, 64) + wt[j]) + emis;
            if (cand > best) { best = cand; bidx = j; }
        }
        bool m = t < len;
        if (lane < 32) hist[t - 1][k] = (unsigned char)(m ? bidx : k);
        score = m ? best : score;
    }
    score += et[k];
    float bv = -3.4e38f; int btag = 0;
    #pragma unroll
    for (int j = 0; j < 32; ++j) {
        float v = __shfl(score, j, 64);
        if (v > bv) { bv = v; btag = j; }
    }
    __syncthreads();
    if (lane == 0) {
        int tag = btag;
        for (int t = NT - 1; t >= 1; --t) {
            preds[(size_t)b * NT + t] = (t < len) ? (float)tag : 0.f;
            tag = hist[t - 1][tag];
        }
        preds[(size_t)b * NT] = (float)tag;
    }
}

// ---------------------------------------------------------------------------
extern "C" void kernel_launch(void* const* d_in, const int* in_sizes, int n_in,
                              void* d_out, int out_size, void* d_ws, size_t ws_size,
                              hipStream_t stream) {
    (void)in_sizes; (void)n_in; (void)out_size;
    const float* x       = (const float*)d_in[0];
    const int*   lengths = (const int*)d_in[1];
    const float* Wih_f = (const float*)d_in[3];
    const float* Whh_f = (const float*)d_in[4];
    const float* b_f   = (const float*)d_in[5];
    const float* Wih_b = (const float*)d_in[6];
    const float* Whh_b = (const float*)d_in[7];
    const float* b_b   = (const float*)d_in[8];
    const float* W_clf = (const float*)d_in[9];
    const float* b_clf = (const float*)d_in[10];
    const float* st    = (const float*)d_in[11];
    const float* et    = (const float*)d_in[12];
    const float* trans = (const float*)d_in[13];

    float* logits = (float*)d_out;
    float* preds  = logits + (size_t)NBT * NK;

    // scratch inside the (not-yet-written) logits region of d_out (4 MB):
    // ww = 2 MB @0, flags = 1 MB @2 MB. k_clf overwrites after lstm is done.
    float* wwp = logits;
    int*   flg = (int*)(logits + 524288);
    const size_t FLB = (size_t)262144 * 4;            // 2*64*4*512 ints

    const size_t XPB = (size_t)NBT * NG * 4;          // 134,217,728
    bool conc = ws_size >= 2 * XPB;

    char* ws = (char*)d_ws;
    float* xp0 = (float*)ws;
    float* xp1 = conc ? (float*)(ws + XPB) : xp0;
    float *hsF, *hsB; int hstr;
    if (conc) {
        hsF = xp0; hsB = xp1; hstr = NG;              // h aliases gate-i columns
    } else {
        hsF = (float*)(ws + XPB); hsB = hsF + (size_t)NB * NT * NH; hstr = NH;
    }

    hipMemsetAsync(flg, 0, FLB, stream);
    k_wprep3<<<2048, 256, 0, stream>>>(Whh_f, Whh_b, wwp);

    if (conc) {
        k_gemm_f<<<dim3(16, 256), 256, 0, stream>>>(x, Wih_f, Wih_b, b_f, b_b,
                                                    xp0, xp1, 0);
        k_lstm4<<<128, 512, 0, stream>>>(xp0, xp1, wwp, lengths,
                                         hsF, hsB, hstr, flg, 0);
    } else {
        k_gemm_f<<<dim3(8, 256), 256, 0, stream>>>(x, Wih_f, Wih_b, b_f, b_b,
                                                   xp0, xp0, 0);
        k_lstm4<<<64, 512, 0, stream>>>(xp0, xp0, wwp, lengths,
                                        hsF, hsB, hstr, flg, 0);
        k_gemm_f<<<dim3(8, 256), 256, 0, stream>>>(x, Wih_f, Wih_b, b_f, b_b,
                                                   xp0, xp0, 8);
        k_lstm4<<<64, 512, 0, stream>>>(xp0, xp0, wwp, lengths,
                                        hsF, hsB, hstr, flg, 16);
    }
    k_clf<<<256, 256, 0, stream>>>(hsF, hsB, hstr, W_clf, b_clf, logits);
    k_viterbi<<<NB, 64, 0, stream>>>(logits, lengths, st, et, trans, preds);
}

// Round 7
// 4637.675 us; speedup vs baseline: 3.1449x; 1.2447x over previous
//
#include <hip/hip_runtime.h>
#include <math.h>

#define NB 64
#define NT 512
#define ND 512
#define NH 256
#define NG 1024   // 4*H
#define NK 32
#define NBT (NB*NT)
#define NBAT 4    // batches per lstm block

__device__ __forceinline__ float sigf(float x) { return 1.f / (1.f + expf(-x)); }
__device__ __forceinline__ float hsum4(float4 v) { return v.x + v.y + v.z + v.w; }

// ---------------------------------------------------------------------------
// Weight prep (unchanged layout):
// ww[(((dir*4+s)*32 + g*8+j)*512 + tid)*4 + e] = Whh_dir[g*256+s*64+u][part*32+j*4+e]
//   where tid = part*64+u
// ---------------------------------------------------------------------------
__global__ void k_wprep3(const float* __restrict__ Wf, const float* __restrict__ Wb,
                         float* __restrict__ ww) {
    int f = blockIdx.x * 256 + threadIdx.x;      // 0 .. 524287
    int e   = f & 3;
    int tid = (f >> 2) & 511;
    int gj  = (f >> 11) & 31;
    int s   = (f >> 16) & 3;
    int dir = (f >> 18) & 1;
    int u = tid & 63, part = tid >> 6;
    int g = gj >> 3, j = gj & 7;
    const float* W = dir ? Wb : Wf;
    int row = g * 256 + s * 64 + u;
    int col = part * 32 + j * 4 + e;
    ww[f] = W[row * 256 + col];
}

// ---------------------------------------------------------------------------
// Fused input projection GEMM (both dirs): xp_dir = x @ Wih_dir^T + b_dir
// ---------------------------------------------------------------------------
__global__ __launch_bounds__(256, 4)
void k_gemm_f(const float* __restrict__ x, const float* __restrict__ Wf,
              const float* __restrict__ Wb, const float* __restrict__ bf,
              const float* __restrict__ bb, float* __restrict__ xpF,
              float* __restrict__ xpB, int bxBase) {
    __shared__ float As[16][132];
    __shared__ float Bs[16][132];
    int tid = threadIdx.x;
    int bx = blockIdx.x + bxBase;
    int dir = bx >> 3;
    const float* W    = dir ? Wb : Wf;
    const float* bias = dir ? bb : bf;
    float* xp         = dir ? xpB : xpF;
    int r0 = blockIdx.y << 7;
    int g0 = (bx & 7) << 7;
    int rl = tid >> 1, k8 = (tid & 1) << 3;
    const float* xa = x + (size_t)(r0 + rl) * ND + k8;
    const float* wa = W + (size_t)(g0 + rl) * ND + k8;
    int tx = tid & 15, ty = tid >> 4;
    float acc[8][8] = {};
    for (int kt = 0; kt < ND; kt += 16) {
        float4 a0 = *(const float4*)(xa + kt);
        float4 a1 = *(const float4*)(xa + kt + 4);
        float4 w0 = *(const float4*)(wa + kt);
        float4 w1 = *(const float4*)(wa + kt + 4);
        As[k8+0][rl]=a0.x; As[k8+1][rl]=a0.y; As[k8+2][rl]=a0.z; As[k8+3][rl]=a0.w;
        As[k8+4][rl]=a1.x; As[k8+5][rl]=a1.y; As[k8+6][rl]=a1.z; As[k8+7][rl]=a1.w;
        Bs[k8+0][rl]=w0.x; Bs[k8+1][rl]=w0.y; Bs[k8+2][rl]=w0.z; Bs[k8+3][rl]=w0.w;
        Bs[k8+4][rl]=w1.x; Bs[k8+5][rl]=w1.y; Bs[k8+6][rl]=w1.z; Bs[k8+7][rl]=w1.w;
        __syncthreads();
        #pragma unroll
        for (int kk = 0; kk < 16; ++kk) {
            float4 av0 = *(const float4*)(&As[kk][ty << 3]);
            float4 av1 = *(const float4*)(&As[kk][(ty << 3) + 4]);
            float4 bv0 = *(const float4*)(&Bs[kk][tx << 3]);
            float4 bv1 = *(const float4*)(&Bs[kk][(tx << 3) + 4]);
            float aa[8] = {av0.x, av0.y, av0.z, av0.w, av1.x, av1.y, av1.z, av1.w};
            float bbv[8] = {bv0.x, bv0.y, bv0.z, bv0.w, bv1.x, bv1.y, bv1.z, bv1.w};
            #pragma unroll
            for (int i = 0; i < 8; ++i)
                #pragma unroll
                for (int j = 0; j < 8; ++j)
                    acc[i][j] += aa[i] * bbv[j];
        }
        __syncthreads();
    }
    float bv[8];
    #pragma unroll
    for (int j = 0; j < 8; ++j) bv[j] = bias[g0 + (tx << 3) + j];
    #pragma unroll
    for (int i = 0; i < 8; ++i) {
        float* orow = xp + (size_t)(r0 + (ty << 3) + i) * NG + g0 + (tx << 3);
        float4 o0 = {acc[i][0]+bv[0], acc[i][1]+bv[1], acc[i][2]+bv[2], acc[i][3]+bv[3]};
        float4 o1 = {acc[i][4]+bv[4], acc[i][5]+bv[5], acc[i][6]+bv[6], acc[i][7]+bv[7]};
        *(float4*)orow = o0;
        *(float4*)(orow + 4) = o1;
    }
}

// ---------------------------------------------------------------------------
// LSTM recurrence (structure identical to round 6). Sync overhaul:
//  - poll flags with RELAXED atomic loads (no per-iteration invalidate)
//  - ONE acquire fence per step (staging waves only) after poll barrier
//  - h published with plain stores; barrier (vmcnt drain) then ONE release
//    fence + 4 relaxed flag stores from wave 0
// ---------------------------------------------------------------------------
#define FMA4(A, W, H) { (A).x += (W).x*(H).x; (A).y += (W).y*(H).y; \
                        (A).z += (W).z*(H).z; (A).w += (W).w*(H).w; }

#define DECLR(g) \
    float4 wr##g##_0 = wwp[qb + ((g)*8+0)*512]; \
    float4 wr##g##_1 = wwp[qb + ((g)*8+1)*512]; \
    float4 wr##g##_2 = wwp[qb + ((g)*8+2)*512]; \
    float4 wr##g##_3 = wwp[qb + ((g)*8+3)*512]; \
    float4 wr##g##_4 = wwp[qb + ((g)*8+4)*512];

#define DOTRJ(j) { float4 h_ = *(const float4*)(hb + (j)*4); \
    FMA4(a0, wr0_##j, h_) FMA4(a1, wr1_##j, h_) \
    FMA4(a2, wr2_##j, h_) FMA4(a3, wr3_##j, h_) }

#define DOTLJ(jj, j) { float4 h_ = *(const float4*)(hb + (j)*4); \
    { float4 l_ = lds_w[(0*3+(jj))*512 + tid]; FMA4(a0, l_, h_) } \
    { float4 l_ = lds_w[(1*3+(jj))*512 + tid]; FMA4(a1, l_, h_) } \
    { float4 l_ = lds_w[(2*3+(jj))*512 + tid]; FMA4(a2, l_, h_) } \
    { float4 l_ = lds_w[(3*3+(jj))*512 + tid]; FMA4(a3, l_, h_) } }

#define DOTALL DOTRJ(0) DOTRJ(1) DOTRJ(2) DOTRJ(3) DOTRJ(4) \
               DOTLJ(0,5) DOTLJ(1,6) DOTLJ(2,7)

__global__ void
__attribute__((amdgpu_flat_work_group_size(512, 512)))
k_lstm4(const float* __restrict__ xpF, const float* __restrict__ xpB,
        const float* __restrict__ ww, const int* __restrict__ lengths,
        float* hsF, float* hsB, int hstr, int* flags, int gBase) {
    int bi = blockIdx.x;
    int g   = (bi & 7) + 8 * (bi >> 5) + gBase;  // 0..31: dir*16 + group
    int s   = (bi >> 3) & 3;                     // u-slice; siblings share bi&7 -> same XCD
    int dir = g >> 4;
    int b0  = (g & 15) * NBAT;
    const float* xp = dir ? xpB : xpF;
    float* hsD      = dir ? hsB : hsF;

    int tid = threadIdx.x;
    int u  = tid & 63;
    int wv = tid >> 6;                           // wave = v-chunk (part) 0..7

    __shared__ float4 lds_w[12 * 512];           // 96 KB: w quads j=5..7 per gate
    __shared__ __align__(16) float hfull[NBAT][256];
    __shared__ float4 lds_part[NBAT][8][64];     // 32 KB
    __shared__ int len4[NBAT];

    const float4* wwp = (const float4*)ww;
    int qb = ((dir * 4 + s) * 32) * 512 + tid;

    DECLR(0) DECLR(1) DECLR(2) DECLR(3)          // 20 named quads -> VGPRs
    #pragma unroll
    for (int gg = 0; gg < 4; ++gg)
        #pragma unroll
        for (int jj = 0; jj < 3; ++jj)
            lds_w[(gg * 3 + jj) * 512 + tid] = wwp[qb + (gg * 8 + 5 + jj) * 512];

    if (tid < NBAT) len4[tid] = lengths[b0 + tid];
    ((float*)hfull)[tid] = 0.f;
    ((float*)hfull)[tid + 512] = 0.f;
    float c_state = 0.f;
    __syncthreads();

    // staging assignment (threads 0..191 = waves 0..2): 48 quads per batch
    int stb  = (tid < 192) ? (tid / 48) : 0;
    int stq  = (tid < 192) ? (tid - stb * 48) : 0;
    int stpsi = stq >> 4, stq16 = stq & 15;
    int stsl = stpsi + (stpsi >= s);             // partner slice
    float* stdst = &hfull[stb][stsl * 64 + stq16 * 4];
    const float* stsrc0 = hsD + (size_t)(b0 + stb) * NT * hstr + stsl * 64 + stq16 * 4;

    // poller assignment (threads 0..15)
    int pb = tid & 3, ps = tid >> 2;
    const int* pollp = flags + ((((dir << 6) + b0 + pb) << 2) + ps) * 512;

    // update-wave global h pointer (waves 0..3)
    float* hwp = hsD + (size_t)(b0 + wv) * NT * hstr + (s << 6) + u;
    // release flag pointer (wave 0 lanes 0..3: u = batch)
    int* flrelW0 = flags + ((((dir << 6) + b0 + u) << 2) + s) * 512;

    for (int tt = 0; tt < NT; ++tt) {
        int t = dir ? (NT - 1 - tt) : tt;

        // A: xp prefetch (wave b loads batch b's 4 gate columns)
        float x0 = 0.f, x1 = 0.f, x2 = 0.f, x3 = 0.f;
        if (wv < NBAT) {
            const float* xr = xp + ((size_t)(b0 + wv) * NT + t) * NG + (s << 6) + u;
            x0 = xr[0]; x1 = xr[256]; x2 = xr[512]; x3 = xr[768];
        }
        // B: poll partner flags RELAXED (no invalidate per iteration)
        if (tt > 0 && tid < 16 && ps != s && t < len4[pb]) {
            const int* fp = pollp + (tt - 1);
            while (__hip_atomic_load(fp, __ATOMIC_RELAXED,
                                     __HIP_MEMORY_SCOPE_AGENT) == 0) {}
        }
        __syncthreads();   // C: flags observed block-wide

        // one acquire fence for the staging waves (0..2), once per step
        if (tt > 0 && tid < 192)
            __builtin_amdgcn_fence(__ATOMIC_ACQUIRE, "agent");

        // D: stage partner h into hfull (192 threads, one quad each)
        if (tt > 0 && tid < 192 && t < len4[stb]) {
            int t_prev = dir ? (t + 1) : (t - 1);
            *(float4*)stdst = *(const float4*)(stsrc0 + (size_t)t_prev * hstr);
        }
        __syncthreads();   // E

        // F: 4 dots (block-uniform skip per batch)
        #pragma unroll
        for (int b = 0; b < NBAT; ++b) {
            if (tt > 0 && t < len4[b]) {
                const float* hb = &hfull[b][wv << 5];
                float4 a0 = {0.f,0.f,0.f,0.f}, a1 = a0, a2 = a0, a3 = a0;
                DOTALL
                lds_part[b][wv][u] = make_float4(hsum4(a0), hsum4(a1),
                                                 hsum4(a2), hsum4(a3));
            }
        }
        __syncthreads();   // G

        // H: update (wave b owns batch b); plain global h store
        if (wv < NBAT) {
            bool act = t < len4[wv];
            float pi, pf, pg, po;
            if (tt > 0 && act) {
                float4 q0 = lds_part[wv][0][u], q1 = lds_part[wv][1][u];
                float4 q2 = lds_part[wv][2][u], q3 = lds_part[wv][3][u];
                float4 q4 = lds_part[wv][4][u], q5 = lds_part[wv][5][u];
                float4 q6 = lds_part[wv][6][u], q7 = lds_part[wv][7][u];
                pi = q0.x+q1.x+q2.x+q3.x+q4.x+q5.x+q6.x+q7.x + x0;
                pf = q0.y+q1.y+q2.y+q3.y+q4.y+q5.y+q6.y+q7.y + x1;
                pg = q0.z+q1.z+q2.z+q3.z+q4.z+q5.z+q6.z+q7.z + x2;
                po = q0.w+q1.w+q2.w+q3.w+q4.w+q5.w+q6.w+q7.w + x3;
            } else {
                pi = x0; pf = x1; pg = x2; po = x3;
            }
            float h_old = hfull[wv][(s << 6) + u];
            float hv = h_old;
            if (act) {
                float gi = sigf(pi), gf = sigf(pf), gg = tanhf(pg), go = sigf(po);
                c_state = gf * c_state + gi * gg;
                hv = go * tanhf(c_state);
            }
            hfull[wv][(s << 6) + u] = hv;
            hwp[(size_t)t * hstr] = hv;          // publish to partners
        }
        __syncthreads();   // I: vmcnt drained for ALL waves' h stores

        // J: one release fence + 4 relaxed flag stores (wave 0)
        if (wv == 0) {
            __builtin_amdgcn_fence(__ATOMIC_RELEASE, "agent");
            if (u < NBAT)
                __hip_atomic_store(flrelW0 + tt, 1, __ATOMIC_RELAXED,
                                   __HIP_MEMORY_SCOPE_AGENT);
        }
    }
}

// ---------------------------------------------------------------------------
// Classifier GEMM: logits[r][kk] = sum_j concat(hsF,hsB)[r][j]*W_clf[kk][j]+b
// ---------------------------------------------------------------------------
__global__ __launch_bounds__(256, 4)
void k_clf(const float* __restrict__ hsF, const float* __restrict__ hsB,
           int hstr, const float* __restrict__ Wclf, const float* __restrict__ bclf,
           float* __restrict__ logits) {
    __shared__ float wt[512 * 32];   // 64 KB  [j][kk]
    __shared__ float xt[32 * 128];   // 16 KB  [j'][r]
    int tid = threadIdx.x;
    int r0 = blockIdx.x << 7;
    #pragma unroll
    for (int e = 0; e < 64; ++e) {
        int idx = e * 256 + tid;           // flat over [32][512]
        int kk = idx >> 9, j = idx & 511;
        wt[j * 32 + kk] = Wclf[idx];
    }
    int rl = tid >> 1, half = tid & 1;
    int kk = tid & 31, rg = tid >> 5;
    float acc[16] = {};
    for (int jc = 0; jc < 16; ++jc) {
        const float* src = (jc < 8 ? hsF : hsB) +
                           (size_t)(r0 + rl) * hstr + ((jc & 7) << 5) + (half << 4);
        float4 v0 = *(const float4*)(src + 0);
        float4 v1 = *(const float4*)(src + 4);
        float4 v2 = *(const float4*)(src + 8);
        float4 v3 = *(const float4*)(src + 12);
        __syncthreads();
        int jb = half << 4;
        xt[(jb+ 0)*128 + rl] = v0.x; xt[(jb+ 1)*128 + rl] = v0.y;
        xt[(jb+ 2)*128 + rl] = v0.z; xt[(jb+ 3)*128 + rl] = v0.w;
        xt[(jb+ 4)*128 + rl] = v1.x; xt[(jb+ 5)*128 + rl] = v1.y;
        xt[(jb+ 6)*128 + rl] = v1.z; xt[(jb+ 7)*128 + rl] = v1.w;
        xt[(jb+ 8)*128 + rl] = v2.x; xt[(jb+ 9)*128 + rl] = v2.y;
        xt[(jb+10)*128 + rl] = v2.z; xt[(jb+11)*128 + rl] = v2.w;
        xt[(jb+12)*128 + rl] = v3.x; xt[(jb+13)*128 + rl] = v3.y;
        xt[(jb+14)*128 + rl] = v3.z; xt[(jb+15)*128 + rl] = v3.w;
        __syncthreads();
        #pragma unroll
        for (int jp = 0; jp < 32; ++jp) {
            float w = wt[(jc * 32 + jp) * 32 + kk];
            const float* xr = &xt[jp * 128 + rg * 16];
            float4 x0 = *(const float4*)(xr + 0);
            float4 x1 = *(const float4*)(xr + 4);
            float4 x2 = *(const float4*)(xr + 8);
            float4 x3 = *(const float4*)(xr + 12);
            acc[ 0] += x0.x*w; acc[ 1] += x0.y*w; acc[ 2] += x0.z*w; acc[ 3] += x0.w*w;
            acc[ 4] += x1.x*w; acc[ 5] += x1.y*w; acc[ 6] += x1.z*w; acc[ 7] += x1.w*w;
            acc[ 8] += x2.x*w; acc[ 9] += x2.y*w; acc[10] += x2.z*w; acc[11] += x2.w*w;
            acc[12] += x3.x*w; acc[13] += x3.y*w; acc[14] += x3.z*w; acc[15] += x3.w*w;
        }
    }
    float bb = bclf[kk];
    #pragma unroll
    for (int i = 0; i < 16; ++i)
        logits[(size_t)(r0 + rg * 16 + i) * NK + kk] = acc[i] + bb;
}

// ---------------------------------------------------------------------------
// Viterbi: one wave per batch, ref-exact rounding order
// ---------------------------------------------------------------------------
__global__ __launch_bounds__(64)
void k_viterbi(const float* __restrict__ logits, const int* __restrict__ lengths,
               const float* __restrict__ st, const float* __restrict__ et,
               const float* __restrict__ trans, float* __restrict__ preds) {
    int b = blockIdx.x, lane = threadIdx.x;
    __shared__ unsigned char hist[NT - 1][NK];
    int len = lengths[b];
    int k = lane & 31;
    float wt[32];
    #pragma unroll
    for (int j = 0; j < 32; ++j) wt[j] = trans[j * NK + k];
    const float* lg = logits + (size_t)b * NT * NK;
    float score = st[k] + lg[k];
    for (int t = 1; t < NT; ++t) {
        float emis = lg[t * NK + k];
        float best = -3.4e38f; int bidx = 0;
        #pragma unroll
        for (int j = 0; j < 32; ++j) {
            float cand = (__shfl(score, j, 64) + wt[j]) + emis;
            if (cand > best) { best = cand; bidx = j; }
        }
        bool m = t < len;
        if (lane < 32) hist[t - 1][k] = (unsigned char)(m ? bidx : k);
        score = m ? best : score;
    }
    score += et[k];
    float bv = -3.4e38f; int btag = 0;
    #pragma unroll
    for (int j = 0; j < 32; ++j) {
        float v = __shfl(score, j, 64);
        if (v > bv) { bv = v; btag = j; }
    }
    __syncthreads();
    if (lane == 0) {
        int tag = btag;
        for (int t = NT - 1; t >= 1; --t) {
            preds[(size_t)b * NT + t] = (t < len) ? (float)tag : 0.f;
            tag = hist[t - 1][tag];
        }
        preds[(size_t)b * NT] = (float)tag;
    }
}

// ---------------------------------------------------------------------------
extern "C" void kernel_launch(void* const* d_in, const int* in_sizes, int n_in,
                              void* d_out, int out_size, void* d_ws, size_t ws_size,
                              hipStream_t stream) {
    (void)in_sizes; (void)n_in; (void)out_size;
    const float* x       = (const float*)d_in[0];
    const int*   lengths = (const int*)d_in[1];
    const float* Wih_f = (const float*)d_in[3];
    const float* Whh_f = (const float*)d_in[4];
    const float* b_f   = (const float*)d_in[5];
    const float* Wih_b = (const float*)d_in[6];
    const float* Whh_b = (const float*)d_in[7];
    const float* b_b   = (const float*)d_in[8];
    const float* W_clf = (const float*)d_in[9];
    const float* b_clf = (const float*)d_in[10];
    const float* st    = (const float*)d_in[11];
    const float* et    = (const float*)d_in[12];
    const float* trans = (const float*)d_in[13];

    float* logits = (float*)d_out;
    float* preds  = logits + (size_t)NBT * NK;

    // scratch inside the (not-yet-written) logits region of d_out (4 MB):
    // ww = 2 MB @0, flags = 1 MB @2 MB. k_clf overwrites after lstm is done.
    float* wwp = logits;
    int*   flg = (int*)(logits + 524288);
    const size_t FLB = (size_t)262144 * 4;            // 2*64*4*512 ints

    const size_t XPB = (size_t)NBT * NG * 4;          // 134,217,728
    bool conc = ws_size >= 2 * XPB;

    char* ws = (char*)d_ws;
    float* xp0 = (float*)ws;
    float* xp1 = conc ? (float*)(ws + XPB) : xp0;
    float *hsF, *hsB; int hstr;
    if (conc) {
        hsF = xp0; hsB = xp1; hstr = NG;              // h aliases gate-i columns
    } else {
        hsF = (float*)(ws + XPB); hsB = hsF + (size_t)NB * NT * NH; hstr = NH;
    }

    hipMemsetAsync(flg, 0, FLB, stream);
    k_wprep3<<<2048, 256, 0, stream>>>(Whh_f, Whh_b, wwp);

    if (conc) {
        k_gemm_f<<<dim3(16, 256), 256, 0, stream>>>(x, Wih_f, Wih_b, b_f, b_b,
                                                    xp0, xp1, 0);
        k_lstm4<<<128, 512, 0, stream>>>(xp0, xp1, wwp, lengths,
                                         hsF, hsB, hstr, flg, 0);
    } else {
        k_gemm_f<<<dim3(8, 256), 256, 0, stream>>>(x, Wih_f, Wih_b, b_f, b_b,
                                                   xp0, xp0, 0);
        k_lstm4<<<64, 512, 0, stream>>>(xp0, xp0, wwp, lengths,
                                        hsF, hsB, hstr, flg, 0);
        k_gemm_f<<<dim3(8, 256), 256, 0, stream>>>(x, Wih_f, Wih_b, b_f, b_b,
                                                   xp0, xp0, 8);
        k_lstm4<<<64, 512, 0, stream>>>(xp0, xp0, wwp, lengths,
                                        hsF, hsB, hstr, flg, 16);
    }
    k_clf<<<256, 256, 0, stream>>>(hsF, hsB, hstr, W_clf, b_clf, logits);
    k_viterbi<<<NB, 64, 0, stream>>>(logits, lengths, st, et, trans, preds);
}

// Round 8
// 3196.846 us; speedup vs baseline: 4.5624x; 1.4507x over previous
//
#include <hip/hip_runtime.h>
#include <math.h>

#define NB 64
#define NT 512
#define ND 512
#define NH 256
#define NG 1024   // 4*H
#define NK 32
#define NBT (NB*NT)
#define NBAT 4    // batches per lstm block

__device__ __forceinline__ float sigf(float x) { return 1.f / (1.f + expf(-x)); }
__device__ __forceinline__ float hsum4(float4 v) { return v.x + v.y + v.z + v.w; }

// ---------------------------------------------------------------------------
// Weight prep (unchanged layout):
// ww[(((dir*4+s)*32 + g*8+j)*512 + tid)*4 + e] = Whh_dir[g*256+s*64+u][part*32+j*4+e]
//   where tid = part*64+u
// ---------------------------------------------------------------------------
__global__ void k_wprep3(const float* __restrict__ Wf, const float* __restrict__ Wb,
                         float* __restrict__ ww) {
    int f = blockIdx.x * 256 + threadIdx.x;      // 0 .. 524287
    int e   = f & 3;
    int tid = (f >> 2) & 511;
    int gj  = (f >> 11) & 31;
    int s   = (f >> 16) & 3;
    int dir = (f >> 18) & 1;
    int u = tid & 63, part = tid >> 6;
    int g = gj >> 3, j = gj & 7;
    const float* W = dir ? Wb : Wf;
    int row = g * 256 + s * 64 + u;
    int col = part * 32 + j * 4 + e;
    ww[f] = W[row * 256 + col];
}

// ---------------------------------------------------------------------------
// Fused input projection GEMM (both dirs): xp_dir = x @ Wih_dir^T + b_dir
// ---------------------------------------------------------------------------
__global__ __launch_bounds__(256, 4)
void k_gemm_f(const float* __restrict__ x, const float* __restrict__ Wf,
              const float* __restrict__ Wb, const float* __restrict__ bf,
              const float* __restrict__ bb, float* __restrict__ xpF,
              float* __restrict__ xpB, int bxBase) {
    __shared__ float As[16][132];
    __shared__ float Bs[16][132];
    int tid = threadIdx.x;
    int bx = blockIdx.x + bxBase;
    int dir = bx >> 3;
    const float* W    = dir ? Wb : Wf;
    const float* bias = dir ? bb : bf;
    float* xp         = dir ? xpB : xpF;
    int r0 = blockIdx.y << 7;
    int g0 = (bx & 7) << 7;
    int rl = tid >> 1, k8 = (tid & 1) << 3;
    const float* xa = x + (size_t)(r0 + rl) * ND + k8;
    const float* wa = W + (size_t)(g0 + rl) * ND + k8;
    int tx = tid & 15, ty = tid >> 4;
    float acc[8][8] = {};
    for (int kt = 0; kt < ND; kt += 16) {
        float4 a0 = *(const float4*)(xa + kt);
        float4 a1 = *(const float4*)(xa + kt + 4);
        float4 w0 = *(const float4*)(wa + kt);
        float4 w1 = *(const float4*)(wa + kt + 4);
        As[k8+0][rl]=a0.x; As[k8+1][rl]=a0.y; As[k8+2][rl]=a0.z; As[k8+3][rl]=a0.w;
        As[k8+4][rl]=a1.x; As[k8+5][rl]=a1.y; As[k8+6][rl]=a1.z; As[k8+7][rl]=a1.w;
        Bs[k8+0][rl]=w0.x; Bs[k8+1][rl]=w0.y; Bs[k8+2][rl]=w0.z; Bs[k8+3][rl]=w0.w;
        Bs[k8+4][rl]=w1.x; Bs[k8+5][rl]=w1.y; Bs[k8+6][rl]=w1.z; Bs[k8+7][rl]=w1.w;
        __syncthreads();
        #pragma unroll
        for (int kk = 0; kk < 16; ++kk) {
            float4 av0 = *(const float4*)(&As[kk][ty << 3]);
            float4 av1 = *(const float4*)(&As[kk][(ty << 3) + 4]);
            float4 bv0 = *(const float4*)(&Bs[kk][tx << 3]);
            float4 bv1 = *(const float4*)(&Bs[kk][(tx << 3) + 4]);
            float aa[8] = {av0.x, av0.y, av0.z, av0.w, av1.x, av1.y, av1.z, av1.w};
            float bbv[8] = {bv0.x, bv0.y, bv0.z, bv0.w, bv1.x, bv1.y, bv1.z, bv1.w};
            #pragma unroll
            for (int i = 0; i < 8; ++i)
                #pragma unroll
                for (int j = 0; j < 8; ++j)
                    acc[i][j] += aa[i] * bbv[j];
        }
        __syncthreads();
    }
    float bv[8];
    #pragma unroll
    for (int j = 0; j < 8; ++j) bv[j] = bias[g0 + (tx << 3) + j];
    #pragma unroll
    for (int i = 0; i < 8; ++i) {
        float* orow = xp + (size_t)(r0 + (ty << 3) + i) * NG + g0 + (tx << 3);
        float4 o0 = {acc[i][0]+bv[0], acc[i][1]+bv[1], acc[i][2]+bv[2], acc[i][3]+bv[3]};
        float4 o1 = {acc[i][4]+bv[4], acc[i][5]+bv[5], acc[i][6]+bv[6], acc[i][7]+bv[7]};
        *(float4*)orow = o0;
        *(float4*)(orow + 4) = o1;
    }
}

// ---------------------------------------------------------------------------
// LSTM recurrence (structure identical to round 7) with FENCE-FREE exchange:
//  - h published via RELAXED agent-scope atomic stores (coherence-point routed)
//  - partner h staged via 64-bit RELAXED agent-scope atomic loads
//  - flags relaxed atomics; ordering via the existing __syncthreads (each
//    emits s_waitcnt vmcnt(0) before s_barrier -> stores complete before
//    flag release; flag observed before stage loads issue)
//  - NO cache-maintenance fences anywhere in the loop
// ---------------------------------------------------------------------------
#define FMA4(A, W, H) { (A).x += (W).x*(H).x; (A).y += (W).y*(H).y; \
                        (A).z += (W).z*(H).z; (A).w += (W).w*(H).w; }

#define DECLR(g) \
    float4 wr##g##_0 = wwp[qb + ((g)*8+0)*512]; \
    float4 wr##g##_1 = wwp[qb + ((g)*8+1)*512]; \
    float4 wr##g##_2 = wwp[qb + ((g)*8+2)*512]; \
    float4 wr##g##_3 = wwp[qb + ((g)*8+3)*512]; \
    float4 wr##g##_4 = wwp[qb + ((g)*8+4)*512];

#define DOTRJ(j) { float4 h_ = *(const float4*)(hb + (j)*4); \
    FMA4(a0, wr0_##j, h_) FMA4(a1, wr1_##j, h_) \
    FMA4(a2, wr2_##j, h_) FMA4(a3, wr3_##j, h_) }

#define DOTLJ(jj, j) { float4 h_ = *(const float4*)(hb + (j)*4); \
    { float4 l_ = lds_w[(0*3+(jj))*512 + tid]; FMA4(a0, l_, h_) } \
    { float4 l_ = lds_w[(1*3+(jj))*512 + tid]; FMA4(a1, l_, h_) } \
    { float4 l_ = lds_w[(2*3+(jj))*512 + tid]; FMA4(a2, l_, h_) } \
    { float4 l_ = lds_w[(3*3+(jj))*512 + tid]; FMA4(a3, l_, h_) } }

#define DOTALL DOTRJ(0) DOTRJ(1) DOTRJ(2) DOTRJ(3) DOTRJ(4) \
               DOTLJ(0,5) DOTLJ(1,6) DOTLJ(2,7)

__global__ void
__attribute__((amdgpu_flat_work_group_size(512, 512)))
k_lstm4(const float* __restrict__ xpF, const float* __restrict__ xpB,
        const float* __restrict__ ww, const int* __restrict__ lengths,
        float* hsF, float* hsB, int hstr, int* flags, int gBase) {
    int bi = blockIdx.x;
    int g   = (bi & 7) + 8 * (bi >> 5) + gBase;  // 0..31: dir*16 + group
    int s   = (bi >> 3) & 3;                     // u-slice; siblings share bi&7
    int dir = g >> 4;
    int b0  = (g & 15) * NBAT;
    const float* xp = dir ? xpB : xpF;
    float* hsD      = dir ? hsB : hsF;

    int tid = threadIdx.x;
    int u  = tid & 63;
    int wv = tid >> 6;                           // wave = v-chunk (part) 0..7

    __shared__ float4 lds_w[12 * 512];           // 96 KB: w quads j=5..7 per gate
    __shared__ __align__(16) float hfull[NBAT][256];
    __shared__ float4 lds_part[NBAT][8][64];     // 32 KB
    __shared__ int len4[NBAT];

    const float4* wwp = (const float4*)ww;
    int qb = ((dir * 4 + s) * 32) * 512 + tid;

    DECLR(0) DECLR(1) DECLR(2) DECLR(3)          // 20 named quads -> VGPRs
    #pragma unroll
    for (int gg = 0; gg < 4; ++gg)
        #pragma unroll
        for (int jj = 0; jj < 3; ++jj)
            lds_w[(gg * 3 + jj) * 512 + tid] = wwp[qb + (gg * 8 + 5 + jj) * 512];

    if (tid < NBAT) len4[tid] = lengths[b0 + tid];
    ((float*)hfull)[tid] = 0.f;
    ((float*)hfull)[tid + 512] = 0.f;
    float c_state = 0.f;
    __syncthreads();

    // staging assignment (threads 0..383 = waves 0..5): 96 ulongs per batch
    // (3 partner slices x 64 floats = 32 ulongs per slice)
    int sb   = tid / 96;                         // batch (tid<384)
    int sr   = tid - sb * 96;
    int spsi = sr >> 5, sq = sr & 31;
    int ssl  = spsi + (spsi >= s);               // partner slice
    unsigned long long* sdst =
        (unsigned long long*)&hfull[sb & 3][ssl * 64 + sq * 2];
    const float* ssrc0 = hsD + (size_t)(b0 + (sb & 3)) * NT * hstr + ssl * 64 + sq * 2;

    // poller assignment (threads 0..15)
    int pb = tid & 3, ps = tid >> 2;
    const int* pollp = flags + ((((dir << 6) + b0 + pb) << 2) + ps) * 512;

    // update-wave global h pointer (waves 0..3)
    float* hwp = hsD + (size_t)(b0 + wv) * NT * hstr + (s << 6) + u;
    // release flag pointer (wave 0 lanes 0..3: u = batch)
    int* flrelW0 = flags + ((((dir << 6) + b0 + u) << 2) + s) * 512;

    for (int tt = 0; tt < NT; ++tt) {
        int t = dir ? (NT - 1 - tt) : tt;

        // A: xp prefetch (wave b loads batch b's 4 gate columns)
        float x0 = 0.f, x1 = 0.f, x2 = 0.f, x3 = 0.f;
        if (wv < NBAT) {
            const float* xr = xp + ((size_t)(b0 + wv) * NT + t) * NG + (s << 6) + u;
            x0 = xr[0]; x1 = xr[256]; x2 = xr[512]; x3 = xr[768];
        }
        // B: poll partner flags RELAXED
        if (tt > 0 && tid < 16 && ps != s && t < len4[pb]) {
            const int* fp = pollp + (tt - 1);
            while (__hip_atomic_load(fp, __ATOMIC_RELAXED,
                                     __HIP_MEMORY_SCOPE_AGENT) == 0) {}
        }
        __syncthreads();   // C: flag loads complete block-wide (vmcnt drained)

        // D: stage partner h via 64-bit relaxed atomic loads (coherent path)
        if (tt > 0 && tid < 384 && t < len4[sb]) {
            int t_prev = dir ? (t + 1) : (t - 1);
            unsigned long long v = __hip_atomic_load(
                (const unsigned long long*)(ssrc0 + (size_t)t_prev * hstr),
                __ATOMIC_RELAXED, __HIP_MEMORY_SCOPE_AGENT);
            *sdst = v;
        }
        __syncthreads();   // E

        // F: 4 dots (block-uniform skip per batch)
        #pragma unroll
        for (int b = 0; b < NBAT; ++b) {
            if (tt > 0 && t < len4[b]) {
                const float* hb = &hfull[b][wv << 5];
                float4 a0 = {0.f,0.f,0.f,0.f}, a1 = a0, a2 = a0, a3 = a0;
                DOTALL
                lds_part[b][wv][u] = make_float4(hsum4(a0), hsum4(a1),
                                                 hsum4(a2), hsum4(a3));
            }
        }
        __syncthreads();   // G

        // H: update (wave b owns batch b); publish h via relaxed atomic store
        if (wv < NBAT) {
            bool act = t < len4[wv];
            float pi, pf, pg, po;
            if (tt > 0 && act) {
                float4 q0 = lds_part[wv][0][u], q1 = lds_part[wv][1][u];
                float4 q2 = lds_part[wv][2][u], q3 = lds_part[wv][3][u];
                float4 q4 = lds_part[wv][4][u], q5 = lds_part[wv][5][u];
                float4 q6 = lds_part[wv][6][u], q7 = lds_part[wv][7][u];
                pi = q0.x+q1.x+q2.x+q3.x+q4.x+q5.x+q6.x+q7.x + x0;
                pf = q0.y+q1.y+q2.y+q3.y+q4.y+q5.y+q6.y+q7.y + x1;
                pg = q0.z+q1.z+q2.z+q3.z+q4.z+q5.z+q6.z+q7.z + x2;
                po = q0.w+q1.w+q2.w+q3.w+q4.w+q5.w+q6.w+q7.w + x3;
            } else {
                pi = x0; pf = x1; pg = x2; po = x3;
            }
            float h_old = hfull[wv][(s << 6) + u];
            float hv = h_old;
            if (act) {
                float gi = sigf(pi), gf = sigf(pf), gg = tanhf(pg), go = sigf(po);
                c_state = gf * c_state + gi * gg;
                hv = go * tanhf(c_state);
            }
            hfull[wv][(s << 6) + u] = hv;
            __hip_atomic_store(hwp + (size_t)t * hstr, hv,
                               __ATOMIC_RELAXED, __HIP_MEMORY_SCOPE_AGENT);
        }
        __syncthreads();   // I: all waves' h atomic stores complete (vmcnt)

        // J: relaxed flag release (wave 0 lanes 0..3)
        if (wv == 0 && u < NBAT)
            __hip_atomic_store(flrelW0 + tt, 1, __ATOMIC_RELAXED,
                               __HIP_MEMORY_SCOPE_AGENT);
    }
}

// ---------------------------------------------------------------------------
// Classifier GEMM: logits[r][kk] = sum_j concat(hsF,hsB)[r][j]*W_clf[kk][j]+b
// ---------------------------------------------------------------------------
__global__ __launch_bounds__(256, 4)
void k_clf(const float* __restrict__ hsF, const float* __restrict__ hsB,
           int hstr, const float* __restrict__ Wclf, const float* __restrict__ bclf,
           float* __restrict__ logits) {
    __shared__ float wt[512 * 32];   // 64 KB  [j][kk]
    __shared__ float xt[32 * 128];   // 16 KB  [j'][r]
    int tid = threadIdx.x;
    int r0 = blockIdx.x << 7;
    #pragma unroll
    for (int e = 0; e < 64; ++e) {
        int idx = e * 256 + tid;           // flat over [32][512]
        int kk = idx >> 9, j = idx & 511;
        wt[j * 32 + kk] = Wclf[idx];
    }
    int rl = tid >> 1, half = tid & 1;
    int kk = tid & 31, rg = tid >> 5;
    float acc[16] = {};
    for (int jc = 0; jc < 16; ++jc) {
        const float* src = (jc < 8 ? hsF : hsB) +
                           (size_t)(r0 + rl) * hstr + ((jc & 7) << 5) + (half << 4);
        float4 v0 = *(const float4*)(src + 0);
        float4 v1 = *(const float4*)(src + 4);
        float4 v2 = *(const float4*)(src + 8);
        float4 v3 = *(const float4*)(src + 12);
        __syncthreads();
        int jb = half << 4;
        xt[(jb+ 0)*128 + rl] = v0.x; xt[(jb+ 1)*128 + rl] = v0.y;
        xt[(jb+ 2)*128 + rl] = v0.z; xt[(jb+ 3)*128 + rl] = v0.w;
        xt[(jb+ 4)*128 + rl] = v1.x; xt[(jb+ 5)*128 + rl] = v1.y;
        xt[(jb+ 6)*128 + rl] = v1.z; xt[(jb+ 7)*128 + rl] = v1.w;
        xt[(jb+ 8)*128 + rl] = v2.x; xt[(jb+ 9)*128 + rl] = v2.y;
        xt[(jb+10)*128 + rl] = v2.z; xt[(jb+11)*128 + rl] = v2.w;
        xt[(jb+12)*128 + rl] = v3.x; xt[(jb+13)*128 + rl] = v3.y;
        xt[(jb+14)*128 + rl] = v3.z; xt[(jb+15)*128 + rl] = v3.w;
        __syncthreads();
        #pragma unroll
        for (int jp = 0; jp < 32; ++jp) {
            float w = wt[(jc * 32 + jp) * 32 + kk];
            const float* xr = &xt[jp * 128 + rg * 16];
            float4 x0 = *(const float4*)(xr + 0);
            float4 x1 = *(const float4*)(xr + 4);
            float4 x2 = *(const float4*)(xr + 8);
            float4 x3 = *(const float4*)(xr + 12);
            acc[ 0] += x0.x*w; acc[ 1] += x0.y*w; acc[ 2] += x0.z*w; acc[ 3] += x0.w*w;
            acc[ 4] += x1.x*w; acc[ 5] += x1.y*w; acc[ 6] += x1.z*w; acc[ 7] += x1.w*w;
            acc[ 8] += x2.x*w; acc[ 9] += x2.y*w; acc[10] += x2.z*w; acc[11] += x2.w*w;
            acc[12] += x3.x*w; acc[13] += x3.y*w; acc[14] += x3.z*w; acc[15] += x3.w*w;
        }
    }
    float bb = bclf[kk];
    #pragma unroll
    for (int i = 0; i < 16; ++i)
        logits[(size_t)(r0 + rg * 16 + i) * NK + kk] = acc[i] + bb;
}

// ---------------------------------------------------------------------------
// Viterbi: one wave per batch, ref-exact rounding order
// ---------------------------------------------------------------------------
__global__ __launch_bounds__(64)
void k_viterbi(const float* __restrict__ logits, const int* __restrict__ lengths,
               const float* __restrict__ st, const float* __restrict__ et,
               const float* __restrict__ trans, float* __restrict__ preds) {
    int b = blockIdx.x, lane = threadIdx.x;
    __shared__ unsigned char hist[NT - 1][NK];
    int len = lengths[b];
    int k = lane & 31;
    float wt[32];
    #pragma unroll
    for (int j = 0; j < 32; ++j) wt[j] = trans[j * NK + k];
    const float* lg = logits + (size_t)b * NT * NK;
    float score = st[k] + lg[k];
    for (int t = 1; t < NT; ++t) {
        float emis = lg[t * NK + k];
        float best = -3.4e38f; int bidx = 0;
        #pragma unroll
        for (int j = 0; j < 32; ++j) {
            float cand = (__shfl(score, j, 64) + wt[j]) + emis;
            if (cand > best) { best = cand; bidx = j; }
        }
        bool m = t < len;
        if (lane < 32) hist[t - 1][k] = (unsigned char)(m ? bidx : k);
        score = m ? best : score;
    }
    score += et[k];
    float bv = -3.4e38f; int btag = 0;
    #pragma unroll
    for (int j = 0; j < 32; ++j) {
        float v = __shfl(score, j, 64);
        if (v > bv) { bv = v; btag = j; }
    }
    __syncthreads();
    if (lane == 0) {
        int tag = btag;
        for (int t = NT - 1; t >= 1; --t) {
            preds[(size_t)b * NT + t] = (t < len) ? (float)tag : 0.f;
            tag = hist[t - 1][tag];
        }
        preds[(size_t)b * NT] = (float)tag;
    }
}

// ---------------------------------------------------------------------------
extern "C" void kernel_launch(void* const* d_in, const int* in_sizes, int n_in,
                              void* d_out, int out_size, void* d_ws, size_t ws_size,
                              hipStream_t stream) {
    (void)in_sizes; (void)n_in; (void)out_size;
    const float* x       = (const float*)d_in[0];
    const int*   lengths = (const int*)d_in[1];
    const float* Wih_f = (const float*)d_in[3];
    const float* Whh_f = (const float*)d_in[4];
    const float* b_f   = (const float*)d_in[5];
    const float* Wih_b = (const float*)d_in[6];
    const float* Whh_b = (const float*)d_in[7];
    const float* b_b   = (const float*)d_in[8];
    const float* W_clf = (const float*)d_in[9];
    const float* b_clf = (const float*)d_in[10];
    const float* st    = (const float*)d_in[11];
    const float* et    = (const float*)d_in[12];
    const float* trans = (const float*)d_in[13];

    float* logits = (float*)d_out;
    float* preds  = logits + (size_t)NBT * NK;

    // scratch inside the (not-yet-written) logits region of d_out (4 MB):
    // ww = 2 MB @0, flags = 1 MB @2 MB. k_clf overwrites after lstm is done.
    float* wwp = logits;
    int*   flg = (int*)(logits + 524288);
    const size_t FLB = (size_t)262144 * 4;            // 2*64*4*512 ints

    const size_t XPB = (size_t)NBT * NG * 4;          // 134,217,728
    bool conc = ws_size >= 2 * XPB;

    char* ws = (char*)d_ws;
    float* xp0 = (float*)ws;
    float* xp1 = conc ? (float*)(ws + XPB) : xp0;
    float *hsF, *hsB; int hstr;
    if (conc) {
        hsF = xp0; hsB = xp1; hstr = NG;              // h aliases gate-i columns
    } else {
        hsF = (float*)(ws + XPB); hsB = hsF + (size_t)NB * NT * NH; hstr = NH;
    }

    hipMemsetAsync(flg, 0, FLB, stream);
    k_wprep3<<<2048, 256, 0, stream>>>(Whh_f, Whh_b, wwp);

    if (conc) {
        k_gemm_f<<<dim3(16, 256), 256, 0, stream>>>(x, Wih_f, Wih_b, b_f, b_b,
                                                    xp0, xp1, 0);
        k_lstm4<<<128, 512, 0, stream>>>(xp0, xp1, wwp, lengths,
                                         hsF, hsB, hstr, flg, 0);
    } else {
        k_gemm_f<<<dim3(8, 256), 256, 0, stream>>>(x, Wih_f, Wih_b, b_f, b_b,
                                                   xp0, xp0, 0);
        k_lstm4<<<64, 512, 0, stream>>>(xp0, xp0, wwp, lengths,
                                        hsF, hsB, hstr, flg, 0);
        k_gemm_f<<<dim3(8, 256), 256, 0, stream>>>(x, Wih_f, Wih_b, b_f, b_b,
                                                   xp0, xp0, 8);
        k_lstm4<<<64, 512, 0, stream>>>(xp0, xp0, wwp, lengths,
                                        hsF, hsB, hstr, flg, 16);
    }
    k_clf<<<256, 256, 0, stream>>>(hsF, hsB, hstr, W_clf, b_clf, logits);
    k_viterbi<<<NB, 64, 0, stream>>>(logits, lengths, st, et, trans, preds);
}